// Round 1
// baseline (344.908 us; speedup 1.0000x reference)
//
#include <hip/hip_runtime.h>
#include <math.h>

#define NB 8192
#define ND 64
#define NL 80

#define ITILE 64
#define JCHUNK 128
#define JRANGE 2048
#define NCHUNK (JRANGE / JCHUNK)   // 16
#define JPAD (ND + 4)              // 68 floats: 16B-aligned rows, conflict-light

// order-preserving float <-> uint mapping for atomicMin/Max
__device__ __forceinline__ unsigned ford(float f) {
    unsigned u = __float_as_uint(f);
    return (u & 0x80000000u) ? ~u : (u | 0x80000000u);
}
__device__ __forceinline__ float funord(unsigned u) {
    unsigned v = (u & 0x80000000u) ? (u ^ 0x80000000u) : ~u;
    return __uint_as_float(v);
}

// Pack labels into 80-bit masks via ballot (coalesced), init all stats, zero out.
__global__ __launch_bounds__(256) void k_init(const int* __restrict__ labels,
        ulonglong2* __restrict__ pl, float* __restrict__ sumsq,
        unsigned* __restrict__ mn, unsigned* __restrict__ mx, unsigned* __restrict__ fl,
        float* __restrict__ possum, float* __restrict__ negsum, float* __restrict__ out) {
    int gid = blockIdx.x * 256 + threadIdx.x;
    sumsq[gid] = 0.f; mn[gid] = 0xFFFFFFFFu; mx[gid] = 0u; fl[gid] = 0u;
    possum[gid] = 0.f; negsum[gid] = 0.f;
    if (gid == 0) out[0] = 0.f;

    int lane = threadIdx.x & 63;
    int wid = gid >> 6;                 // 128 waves total
    for (int r = 0; r < 64; ++r) {
        int row = wid * 64 + r;
        const int* lr = labels + (size_t)row * NL;
        int v0 = lr[lane];
        int v1 = (lane < 16) ? lr[64 + lane] : 0;
        unsigned long long lo = __ballot(v0 != 0);
        unsigned long long hi = __ballot(v1 != 0);
        if (lane == 0) { pl[row].x = lo; pl[row].y = hi; }
    }
}

// Pass 1: raw dot tiles -> per-row {sum(s^2), min over pos, max over neg, any-flags}
__global__ __launch_bounds__(256) void k_pass1(const float* __restrict__ F,
        const ulonglong2* __restrict__ pl,
        float* __restrict__ sumsq, unsigned* __restrict__ mn,
        unsigned* __restrict__ mx, unsigned* __restrict__ fl) {
    __shared__ float Fi[ITILE][ND];      // 16 KB, broadcast reads
    __shared__ float Fj[JCHUNK][JPAD];   // 34 KB
    __shared__ ulonglong2 PLj[JCHUNK];   // 2 KB

    const int tid = threadIdx.x;
    const int i0 = blockIdx.y * ITILE;
    const int jbase = blockIdx.x * JRANGE;
    const int jx = tid & 15;
    const int iy = tid >> 4;

#pragma unroll
    for (int t = 0; t < 4; ++t) {
        int e = (tid + t * 256) * 4;
        *(float4*)&Fi[e >> 6][e & 63] = *(const float4*)&F[i0 * ND + e];
    }
    ulonglong2 pi[4];
#pragma unroll
    for (int r = 0; r < 4; ++r) pi[r] = pl[i0 + iy * 4 + r];

    float ssq[4] = {0.f, 0.f, 0.f, 0.f};
    float mnp[4] = {INFINITY, INFINITY, INFINITY, INFINITY};
    float mxn[4] = {-INFINITY, -INFINITY, -INFINITY, -INFINITY};
    unsigned flg[4] = {0u, 0u, 0u, 0u};

    for (int jc = 0; jc < NCHUNK; ++jc) {
        const int j0 = jbase + jc * JCHUNK;
        __syncthreads();
#pragma unroll
        for (int t = 0; t < 8; ++t) {
            int e = (tid + t * 256) * 4;
            *(float4*)&Fj[e >> 6][e & 63] = *(const float4*)&F[j0 * ND + e];
        }
        if (tid < JCHUNK) PLj[tid] = pl[j0 + tid];
        __syncthreads();

        float acc[4][8];
#pragma unroll
        for (int r = 0; r < 4; ++r)
#pragma unroll
            for (int q = 0; q < 8; ++q) acc[r][q] = 0.f;

        for (int d = 0; d < ND; d += 4) {
            float4 va[4], vb[8];
#pragma unroll
            for (int r = 0; r < 4; ++r) va[r] = *(const float4*)&Fi[iy * 4 + r][d];
#pragma unroll
            for (int q = 0; q < 8; ++q) vb[q] = *(const float4*)&Fj[q * 16 + jx][d];
#pragma unroll
            for (int r = 0; r < 4; ++r)
#pragma unroll
                for (int q = 0; q < 8; ++q)
                    acc[r][q] += va[r].x * vb[q].x + va[r].y * vb[q].y +
                                 va[r].z * vb[q].z + va[r].w * vb[q].w;
        }

#pragma unroll
        for (int r = 0; r < 4; ++r) {
#pragma unroll
            for (int q = 0; q < 8; ++q) {
                ulonglong2 pj = PLj[q * 16 + jx];
                bool pos = ((pi[r].x & pj.x) | (pi[r].y & pj.y)) != 0ull;
                float s = acc[r][q];
                ssq[r] += s * s;
                mnp[r] = fminf(mnp[r], pos ? s : INFINITY);
                mxn[r] = fmaxf(mxn[r], pos ? -INFINITY : s);
                flg[r] |= pos ? 1u : 2u;
            }
        }
    }

#pragma unroll
    for (int off = 8; off; off >>= 1) {
#pragma unroll
        for (int r = 0; r < 4; ++r) {
            ssq[r] += __shfl_xor(ssq[r], off);
            mnp[r] = fminf(mnp[r], __shfl_xor(mnp[r], off));
            mxn[r] = fmaxf(mxn[r], __shfl_xor(mxn[r], off));
            flg[r] |= (unsigned)__shfl_xor((int)flg[r], off);
        }
    }
    if (jx == 0) {
#pragma unroll
        for (int r = 0; r < 4; ++r) {
            int i = i0 + iy * 4 + r;
            atomicAdd(&sumsq[i], ssq[r]);
            atomicMin(&mn[i], ford(mnp[r]));
            atomicMax(&mx[i], ford(mxn[r]));
            atomicOr(&fl[i], flg[r]);
        }
    }
}

// Per-row thresholds in RAW-dot space so pass 2 avoids per-element normalization.
__global__ __launch_bounds__(256) void k_finalize(const float* __restrict__ sumsq,
        const unsigned* __restrict__ mn, const unsigned* __restrict__ mx,
        unsigned* __restrict__ fl, float* __restrict__ tneg, float* __restrict__ tpos,
        float* __restrict__ teps, float* __restrict__ invd) {
    int i = blockIdx.x * 256 + threadIdx.x;
    float div = fmaxf(sqrtf(sumsq[i]), 1e-12f);
    float inv = 1.f / div;
    unsigned f = fl[i];
    float mp = funord(mn[i]);       // +inf if no pos at all
    float mneg = funord(mx[i]);     // -inf if no neg
    float eraw = (1.0f - 1e-5f) * div;
    bool hasp = ((f & 1u) != 0u) && (mp < eraw);
    bool hasn = (f & 2u) != 0u;
    float minpos_n = hasp ? mp * inv : INFINITY;
    float maxneg_n = hasn ? mneg * inv : -INFINITY;
    tneg[i] = (minpos_n - 0.1f) * div;   // neg_sel: raw >  tneg
    tpos[i] = (maxneg_n + 0.1f) * div;   // pos_sel: raw <  tpos
    teps[i] = eraw;                      // pos_valid: raw < teps
    invd[i] = inv;
    fl[i] = (hasp ? 1u : 0u) | (hasn ? 2u : 0u);
}

// Pass 2: recompute raw dots, mined-pair exp sums per row.
__global__ __launch_bounds__(256) void k_pass2(const float* __restrict__ F,
        const ulonglong2* __restrict__ pl,
        const float* __restrict__ tneg, const float* __restrict__ tpos,
        const float* __restrict__ teps, const float* __restrict__ invd,
        float* __restrict__ possum, float* __restrict__ negsum) {
    __shared__ float Fi[ITILE][ND];
    __shared__ float Fj[JCHUNK][JPAD];
    __shared__ ulonglong2 PLj[JCHUNK];

    const int tid = threadIdx.x;
    const int i0 = blockIdx.y * ITILE;
    const int jbase = blockIdx.x * JRANGE;
    const int jx = tid & 15;
    const int iy = tid >> 4;

#pragma unroll
    for (int t = 0; t < 4; ++t) {
        int e = (tid + t * 256) * 4;
        *(float4*)&Fi[e >> 6][e & 63] = *(const float4*)&F[i0 * ND + e];
    }
    ulonglong2 pi[4];
    float tn[4], tp[4], te[4], iv[4];
#pragma unroll
    for (int r = 0; r < 4; ++r) {
        int i = i0 + iy * 4 + r;
        pi[r] = pl[i];
        tn[r] = tneg[i]; tp[r] = tpos[i]; te[r] = teps[i]; iv[r] = invd[i];
    }
    float psum[4] = {0.f, 0.f, 0.f, 0.f}, nsum[4] = {0.f, 0.f, 0.f, 0.f};

    for (int jc = 0; jc < NCHUNK; ++jc) {
        const int j0 = jbase + jc * JCHUNK;
        __syncthreads();
#pragma unroll
        for (int t = 0; t < 8; ++t) {
            int e = (tid + t * 256) * 4;
            *(float4*)&Fj[e >> 6][e & 63] = *(const float4*)&F[j0 * ND + e];
        }
        if (tid < JCHUNK) PLj[tid] = pl[j0 + tid];
        __syncthreads();

        float acc[4][8];
#pragma unroll
        for (int r = 0; r < 4; ++r)
#pragma unroll
            for (int q = 0; q < 8; ++q) acc[r][q] = 0.f;

        for (int d = 0; d < ND; d += 4) {
            float4 va[4], vb[8];
#pragma unroll
            for (int r = 0; r < 4; ++r) va[r] = *(const float4*)&Fi[iy * 4 + r][d];
#pragma unroll
            for (int q = 0; q < 8; ++q) vb[q] = *(const float4*)&Fj[q * 16 + jx][d];
#pragma unroll
            for (int r = 0; r < 4; ++r)
#pragma unroll
                for (int q = 0; q < 8; ++q)
                    acc[r][q] += va[r].x * vb[q].x + va[r].y * vb[q].y +
                                 va[r].z * vb[q].z + va[r].w * vb[q].w;
        }

#pragma unroll
        for (int r = 0; r < 4; ++r) {
#pragma unroll
            for (int q = 0; q < 8; ++q) {
                ulonglong2 pj = PLj[q * 16 + jx];
                bool pos = ((pi[r].x & pj.x) | (pi[r].y & pj.y)) != 0ull;
                float s = acc[r][q];
                float sn = s * iv[r];
                bool psel = pos && (s < te[r]) && (s < tp[r]);
                bool nsel = (!pos) && (s > tn[r]);
                // exp(-2*(sn-0.1)) for pos, exp(40*(sn-0.1)) for neg
                float arg = pos ? (0.2f - 2.0f * sn) : (40.0f * sn - 4.0f);
                float ev = __expf(arg);
                psum[r] += psel ? ev : 0.0f;
                nsum[r] += nsel ? ev : 0.0f;
            }
        }
    }

#pragma unroll
    for (int off = 8; off; off >>= 1) {
#pragma unroll
        for (int r = 0; r < 4; ++r) {
            psum[r] += __shfl_xor(psum[r], off);
            nsum[r] += __shfl_xor(nsum[r], off);
        }
    }
    if (jx == 0) {
#pragma unroll
        for (int r = 0; r < 4; ++r) {
            int i = i0 + iy * 4 + r;
            atomicAdd(&possum[i], psum[r]);
            atomicAdd(&negsum[i], nsum[r]);
        }
    }
}

__global__ __launch_bounds__(256) void k_reduce(const float* __restrict__ possum,
        const float* __restrict__ negsum, const unsigned* __restrict__ fl,
        float* __restrict__ out) {
    int i = blockIdx.x * 256 + threadIdx.x;
    unsigned f = fl[i];
    float ps = possum[i], ns = negsum[i];
    bool valid = ((f & 1u) != 0u) && ((f & 2u) != 0u) && (ps > 0.f) && (ns > 0.f);
    float rl = valid ? (0.5f * log1pf(ps) + 0.025f * log1pf(ns)) : 0.f;
#pragma unroll
    for (int off = 32; off; off >>= 1) rl += __shfl_xor(rl, off);
    __shared__ float wsum[4];
    if ((threadIdx.x & 63) == 0) wsum[threadIdx.x >> 6] = rl;
    __syncthreads();
    if (threadIdx.x == 0) {
        float s = wsum[0] + wsum[1] + wsum[2] + wsum[3];
        atomicAdd(out, s * (1.0f / 8192.0f));   // /2^13 is exact per partial
    }
}

extern "C" void kernel_launch(void* const* d_in, const int* in_sizes, int n_in,
                              void* d_out, int out_size, void* d_ws, size_t ws_size,
                              hipStream_t stream) {
    const float* F = (const float*)d_in[0];
    const int* labels = (const int*)d_in[1];
    float* out = (float*)d_out;

    char* w = (char*)d_ws;
    ulonglong2* pl  = (ulonglong2*)w;                    // 131072 B
    float*    sumsq = (float*)   (w + 131072);
    unsigned* mn    = (unsigned*)(w + 163840);
    unsigned* mx    = (unsigned*)(w + 196608);
    unsigned* fl    = (unsigned*)(w + 229376);
    float*    tneg  = (float*)   (w + 262144);
    float*    tpos  = (float*)   (w + 294912);
    float*    teps  = (float*)   (w + 327680);
    float*    invd  = (float*)   (w + 360448);
    float*    possum= (float*)   (w + 393216);
    float*    negsum= (float*)   (w + 425984);           // end 458752 B

    k_init<<<32, 256, 0, stream>>>(labels, pl, sumsq, mn, mx, fl, possum, negsum, out);
    k_pass1<<<dim3(4, 128), 256, 0, stream>>>(F, pl, sumsq, mn, mx, fl);
    k_finalize<<<32, 256, 0, stream>>>(sumsq, mn, mx, fl, tneg, tpos, teps, invd);
    k_pass2<<<dim3(4, 128), 256, 0, stream>>>(F, pl, tneg, tpos, teps, invd, possum, negsum);
    k_reduce<<<32, 256, 0, stream>>>(possum, negsum, fl, out);
}

// Round 2
// 176.265 us; speedup vs baseline: 1.9568x; 1.9568x over previous
//
#include <hip/hip_runtime.h>
#include <math.h>

#define NB 8192
#define ND 64
#define NL 80

typedef __attribute__((ext_vector_type(8))) __bf16 bf16x8;
typedef __attribute__((ext_vector_type(16))) float f32x16;

// order-preserving float <-> uint mapping for atomicMin/Max
__device__ __forceinline__ unsigned ford(float f) {
    unsigned u = __float_as_uint(f);
    return (u & 0x80000000u) ? ~u : (u | 0x80000000u);
}
__device__ __forceinline__ float funord(unsigned u) {
    unsigned v = (u & 0x80000000u) ? (u ^ 0x80000000u) : ~u;
    return __uint_as_float(v);
}
__device__ __forceinline__ unsigned short bf16rne(float x) {
    unsigned u = __float_as_uint(x);
    unsigned r = u + 0x7FFFu + ((u >> 16) & 1u);
    return (unsigned short)(r >> 16);
}
__device__ __forceinline__ float bf16tof(unsigned short h) {
    return __uint_as_float(((unsigned)h) << 16);
}

// Pack labels to 80-bit masks, split F into bf16 hi/lo, init stats, zero out.
__global__ __launch_bounds__(256) void k_init(const float* __restrict__ F,
        const int* __restrict__ labels, ushort4* __restrict__ Fhi, ushort4* __restrict__ Flo,
        ulonglong2* __restrict__ pl, float* __restrict__ sumsq,
        unsigned* __restrict__ mn, unsigned* __restrict__ mx, unsigned* __restrict__ fl,
        float* __restrict__ possum, float* __restrict__ negsum, float* __restrict__ out) {
    int gid = blockIdx.x * 256 + threadIdx.x;   // 8192 threads
    sumsq[gid] = 0.f; mn[gid] = 0xFFFFFFFFu; mx[gid] = 0u; fl[gid] = 0u;
    possum[gid] = 0.f; negsum[gid] = 0.f;
    if (gid == 0) out[0] = 0.f;

    // hi/lo split: 131072 float4 elements, coalesced
    const float4* F4 = (const float4*)F;
#pragma unroll
    for (int t = 0; t < 16; ++t) {
        int idx = t * 8192 + gid;
        float4 v = F4[idx];
        ushort4 h, l;
        h.x = bf16rne(v.x); l.x = bf16rne(v.x - bf16tof(h.x));
        h.y = bf16rne(v.y); l.y = bf16rne(v.y - bf16tof(h.y));
        h.z = bf16rne(v.z); l.z = bf16rne(v.z - bf16tof(h.z));
        h.w = bf16rne(v.w); l.w = bf16rne(v.w - bf16tof(h.w));
        Fhi[idx] = h; Flo[idx] = l;
    }

    int lane = threadIdx.x & 63;
    int wid = gid >> 6;                 // 128 waves total
    for (int r = 0; r < 64; ++r) {
        int row = wid * 64 + r;
        const int* lr = labels + (size_t)row * NL;
        int v0 = lr[lane];
        int v1 = (lane < 16) ? lr[64 + lane] : 0;
        unsigned long long lo = __ballot(v0 != 0);
        unsigned long long hi = __ballot(v1 != 0);
        if (lane == 0) { pl[row].x = lo; pl[row].y = hi; }
    }
}

#define LDS_AHI 0
#define LDS_ALO 16384
#define LDS_BHI 32768
#define LDS_BLO 49152

// Stage 128-row A(j) and B(i) panels, hi+lo, XOR-swizzled (G4: byte ^= (row&7)<<4).
__device__ __forceinline__ void stage_panels(char* lds, const uint4* __restrict__ Fhi4,
        const uint4* __restrict__ Flo4, int i0, int j0, int tid) {
#pragma unroll
    for (int t = 0; t < 4; ++t) {
        int idx = tid + t * 256;          // 0..1023
        int row = idx >> 3, c8 = idx & 7;
        int dst = row * 128 + ((c8 * 16) ^ ((row & 7) << 4));
        *(uint4*)(lds + LDS_AHI + dst) = Fhi4[(j0 + row) * 8 + c8];
        *(uint4*)(lds + LDS_ALO + dst) = Flo4[(j0 + row) * 8 + c8];
        *(uint4*)(lds + LDS_BHI + dst) = Fhi4[(i0 + row) * 8 + c8];
        *(uint4*)(lds + LDS_BLO + dst) = Flo4[(i0 + row) * 8 + c8];
    }
}

// 64x64 per wave: acc[m][n] = sum over 3 splits of Fj-panel x Fi-panel^T.
// C layout (m74/m101): col=lane&31 (i), row=(reg&3)+8*(reg>>2)+4*(lane>>5) (j).
__device__ __forceinline__ void compute_tile(const char* lds, int wr, int wc, int lane,
                                             f32x16 acc[2][2]) {
    const int l31 = lane & 31, lhalf = lane >> 5;
    const int swz = (l31 & 7) << 4;
    const int abase = (wr * 64 + l31) * 128;
    const int bbase = (wc * 64 + l31) * 128;
#pragma unroll
    for (int seg = 0; seg < 3; ++seg) {
        const char* pa = lds + (seg == 2 ? LDS_ALO : LDS_AHI);
        const char* pb = lds + (seg == 1 ? LDS_BLO : LDS_BHI);
#pragma unroll
        for (int ks = 0; ks < 4; ++ks) {
            int off = (ks * 32 + lhalf * 16) ^ swz;
            bf16x8 a0 = *(const bf16x8*)(pa + abase + off);
            bf16x8 a1 = *(const bf16x8*)(pa + abase + 32 * 128 + off);
            bf16x8 b0 = *(const bf16x8*)(pb + bbase + off);
            bf16x8 b1 = *(const bf16x8*)(pb + bbase + 32 * 128 + off);
            acc[0][0] = __builtin_amdgcn_mfma_f32_32x32x16_bf16(a0, b0, acc[0][0], 0, 0, 0);
            acc[0][1] = __builtin_amdgcn_mfma_f32_32x32x16_bf16(a0, b1, acc[0][1], 0, 0, 0);
            acc[1][0] = __builtin_amdgcn_mfma_f32_32x32x16_bf16(a1, b0, acc[1][0], 0, 0, 0);
            acc[1][1] = __builtin_amdgcn_mfma_f32_32x32x16_bf16(a1, b1, acc[1][1], 0, 0, 0);
        }
    }
}

__global__ __launch_bounds__(256, 2) void k_pass1(const uint4* __restrict__ Fhi4,
        const uint4* __restrict__ Flo4, const ulonglong2* __restrict__ pl,
        float* __restrict__ sumsq, unsigned* __restrict__ mn,
        unsigned* __restrict__ mx, unsigned* __restrict__ fl) {
    __shared__ char lds[65536];
    const int tid = threadIdx.x;
    const int i0 = blockIdx.y * 128, j0 = blockIdx.x * 128;
    stage_panels(lds, Fhi4, Flo4, i0, j0, tid);
    __syncthreads();
    const int lane = tid & 63, wid = tid >> 6;
    const int wr = wid >> 1, wc = wid & 1;
    const int l31 = lane & 31, lhalf = lane >> 5;
    f32x16 acc[2][2] = {};
    compute_tile(lds, wr, wc, lane, acc);
    __syncthreads();                      // panels dead; reuse LDS for PLj
    if (tid < 128) *(ulonglong2*)(lds + tid * 16) = pl[j0 + tid];
    __syncthreads();

    ulonglong2 pi[2];
    pi[0] = pl[i0 + wc * 64 + l31];
    pi[1] = pl[i0 + wc * 64 + 32 + l31];
    float ssq[2] = {0.f, 0.f};
    float mnp[2] = {INFINITY, INFINITY};
    float mxn[2] = {-INFINITY, -INFINITY};
    unsigned flg[2] = {0u, 0u};
#pragma unroll
    for (int m = 0; m < 2; ++m) {
#pragma unroll
        for (int reg = 0; reg < 16; ++reg) {
            int jl = wr * 64 + m * 32 + (reg & 3) + 8 * (reg >> 2) + 4 * lhalf;
            ulonglong2 pj = *(const ulonglong2*)(lds + jl * 16);
#pragma unroll
            for (int n = 0; n < 2; ++n) {
                float s = acc[m][n][reg];
                bool pos = (((pi[n].x & pj.x) | (pi[n].y & pj.y)) != 0ull);
                ssq[n] += s * s;
                mnp[n] = fminf(mnp[n], pos ? s : INFINITY);
                mxn[n] = fmaxf(mxn[n], pos ? -INFINITY : s);
                flg[n] |= pos ? 1u : 2u;
            }
        }
    }
#pragma unroll
    for (int n = 0; n < 2; ++n) {
        ssq[n] += __shfl_xor(ssq[n], 32);
        mnp[n] = fminf(mnp[n], __shfl_xor(mnp[n], 32));
        mxn[n] = fmaxf(mxn[n], __shfl_xor(mxn[n], 32));
        flg[n] |= (unsigned)__shfl_xor((int)flg[n], 32);
    }
    if (lane < 32) {
#pragma unroll
        for (int n = 0; n < 2; ++n) {
            int i = i0 + wc * 64 + n * 32 + lane;
            atomicAdd(&sumsq[i], ssq[n]);
            atomicMin(&mn[i], ford(mnp[n]));
            atomicMax(&mx[i], ford(mxn[n]));
            atomicOr(&fl[i], flg[n]);
        }
    }
}

// Per-row thresholds in RAW-dot space (verified round 0).
__global__ __launch_bounds__(256) void k_finalize(const float* __restrict__ sumsq,
        const unsigned* __restrict__ mn, const unsigned* __restrict__ mx,
        unsigned* __restrict__ fl, float* __restrict__ tneg, float* __restrict__ tpos,
        float* __restrict__ teps, float* __restrict__ invd) {
    int i = blockIdx.x * 256 + threadIdx.x;
    float div = fmaxf(sqrtf(sumsq[i]), 1e-12f);
    float inv = 1.f / div;
    unsigned f = fl[i];
    float mp = funord(mn[i]);
    float mneg = funord(mx[i]);
    float eraw = (1.0f - 1e-5f) * div;
    bool hasp = ((f & 1u) != 0u) && (mp < eraw);
    bool hasn = (f & 2u) != 0u;
    float minpos_n = hasp ? mp * inv : INFINITY;
    float maxneg_n = hasn ? mneg * inv : -INFINITY;
    tneg[i] = (minpos_n - 0.1f) * div;   // neg_sel: raw >  tneg
    tpos[i] = (maxneg_n + 0.1f) * div;   // pos_sel: raw <  tpos
    teps[i] = eraw;                      // pos_valid: raw < teps
    invd[i] = inv;
    fl[i] = (hasp ? 1u : 0u) | (hasn ? 2u : 0u);
}

__global__ __launch_bounds__(256, 2) void k_pass2(const uint4* __restrict__ Fhi4,
        const uint4* __restrict__ Flo4, const ulonglong2* __restrict__ pl,
        const float* __restrict__ tneg, const float* __restrict__ tpos,
        const float* __restrict__ teps, const float* __restrict__ invd,
        float* __restrict__ possum, float* __restrict__ negsum) {
    __shared__ char lds[65536];
    const int tid = threadIdx.x;
    const int i0 = blockIdx.y * 128, j0 = blockIdx.x * 128;
    stage_panels(lds, Fhi4, Flo4, i0, j0, tid);
    __syncthreads();
    const int lane = tid & 63, wid = tid >> 6;
    const int wr = wid >> 1, wc = wid & 1;
    const int l31 = lane & 31, lhalf = lane >> 5;
    f32x16 acc[2][2] = {};
    compute_tile(lds, wr, wc, lane, acc);
    __syncthreads();
    if (tid < 128) *(ulonglong2*)(lds + tid * 16) = pl[j0 + tid];
    __syncthreads();

    ulonglong2 pi[2];
    float tn[2], tp[2], te[2], iv[2];
#pragma unroll
    for (int n = 0; n < 2; ++n) {
        int i = i0 + wc * 64 + n * 32 + l31;
        pi[n] = pl[i];
        tn[n] = tneg[i]; tp[n] = tpos[i]; te[n] = teps[i]; iv[n] = invd[i];
    }
    float psum[2] = {0.f, 0.f}, nsum[2] = {0.f, 0.f};
#pragma unroll
    for (int m = 0; m < 2; ++m) {
#pragma unroll
        for (int reg = 0; reg < 16; ++reg) {
            int jl = wr * 64 + m * 32 + (reg & 3) + 8 * (reg >> 2) + 4 * lhalf;
            ulonglong2 pj = *(const ulonglong2*)(lds + jl * 16);
#pragma unroll
            for (int n = 0; n < 2; ++n) {
                float s = acc[m][n][reg];
                bool pos = (((pi[n].x & pj.x) | (pi[n].y & pj.y)) != 0ull);
                float sn = s * iv[n];
                bool psel = pos && (s < te[n]) && (s < tp[n]);
                bool nsel = (!pos) && (s > tn[n]);
                float arg = pos ? fmaf(-2.0f, sn, 0.2f) : fmaf(40.0f, sn, -4.0f);
                float ev = __expf(arg);
                psum[n] += psel ? ev : 0.0f;
                nsum[n] += nsel ? ev : 0.0f;
            }
        }
    }
#pragma unroll
    for (int n = 0; n < 2; ++n) {
        psum[n] += __shfl_xor(psum[n], 32);
        nsum[n] += __shfl_xor(nsum[n], 32);
    }
    if (lane < 32) {
#pragma unroll
        for (int n = 0; n < 2; ++n) {
            int i = i0 + wc * 64 + n * 32 + lane;
            atomicAdd(&possum[i], psum[n]);
            atomicAdd(&negsum[i], nsum[n]);
        }
    }
}

__global__ __launch_bounds__(256) void k_reduce(const float* __restrict__ possum,
        const float* __restrict__ negsum, const unsigned* __restrict__ fl,
        float* __restrict__ out) {
    int i = blockIdx.x * 256 + threadIdx.x;
    unsigned f = fl[i];
    float ps = possum[i], ns = negsum[i];
    bool valid = ((f & 1u) != 0u) && ((f & 2u) != 0u) && (ps > 0.f) && (ns > 0.f);
    float rl = valid ? (0.5f * log1pf(ps) + 0.025f * log1pf(ns)) : 0.f;
#pragma unroll
    for (int off = 32; off; off >>= 1) rl += __shfl_xor(rl, off);
    __shared__ float wsum[4];
    if ((threadIdx.x & 63) == 0) wsum[threadIdx.x >> 6] = rl;
    __syncthreads();
    if (threadIdx.x == 0) {
        float s = wsum[0] + wsum[1] + wsum[2] + wsum[3];
        atomicAdd(out, s * (1.0f / 8192.0f));
    }
}

extern "C" void kernel_launch(void* const* d_in, const int* in_sizes, int n_in,
                              void* d_out, int out_size, void* d_ws, size_t ws_size,
                              hipStream_t stream) {
    const float* F = (const float*)d_in[0];
    const int* labels = (const int*)d_in[1];
    float* out = (float*)d_out;

    char* w = (char*)d_ws;
    ulonglong2* pl  = (ulonglong2*)w;                    // 131072 B
    float*    sumsq = (float*)   (w + 131072);
    unsigned* mn    = (unsigned*)(w + 163840);
    unsigned* mx    = (unsigned*)(w + 196608);
    unsigned* fl    = (unsigned*)(w + 229376);
    float*    tneg  = (float*)   (w + 262144);
    float*    tpos  = (float*)   (w + 294912);
    float*    teps  = (float*)   (w + 327680);
    float*    invd  = (float*)   (w + 360448);
    float*    possum= (float*)   (w + 393216);
    float*    negsum= (float*)   (w + 425984);
    ushort4*  Fhi   = (ushort4*) (w + 458752);           // 1 MB
    ushort4*  Flo   = (ushort4*) (w + 1507328);          // 1 MB, end 2555904

    dim3 g(64, 64);
    k_init<<<32, 256, 0, stream>>>(F, labels, Fhi, Flo, pl, sumsq, mn, mx, fl,
                                   possum, negsum, out);
    k_pass1<<<g, 256, 0, stream>>>((const uint4*)Fhi, (const uint4*)Flo, pl,
                                   sumsq, mn, mx, fl);
    k_finalize<<<32, 256, 0, stream>>>(sumsq, mn, mx, fl, tneg, tpos, teps, invd);
    k_pass2<<<g, 256, 0, stream>>>((const uint4*)Fhi, (const uint4*)Flo, pl,
                                   tneg, tpos, teps, invd, possum, negsum);
    k_reduce<<<32, 256, 0, stream>>>(possum, negsum, fl, out);
}

// Round 3
// 121.955 us; speedup vs baseline: 2.8282x; 1.4453x over previous
//
#include <hip/hip_runtime.h>
#include <math.h>

#define NB 8192
#define ND 64
#define NL 80

typedef __attribute__((ext_vector_type(8))) __bf16 bf16x8;
typedef __attribute__((ext_vector_type(16))) float f32x16;

// order-preserving float <-> uint mapping for atomicMin/Max
__device__ __forceinline__ unsigned ford(float f) {
    unsigned u = __float_as_uint(f);
    return (u & 0x80000000u) ? ~u : (u | 0x80000000u);
}
__device__ __forceinline__ float funord(unsigned u) {
    unsigned v = (u & 0x80000000u) ? (u ^ 0x80000000u) : ~u;
    return __uint_as_float(v);
}
__device__ __forceinline__ unsigned short bf16rne(float x) {
    unsigned u = __float_as_uint(x);
    unsigned r = u + 0x7FFFu + ((u >> 16) & 1u);
    return (unsigned short)(r >> 16);
}
__device__ __forceinline__ float bf16tof(unsigned short h) {
    return __uint_as_float(((unsigned)h) << 16);
}

// Pack labels to 80-bit masks, split F into bf16 hi/lo, init stats, zero out.
__global__ __launch_bounds__(256) void k_init(const float* __restrict__ F,
        const int* __restrict__ labels, ushort4* __restrict__ Fhi, ushort4* __restrict__ Flo,
        ulonglong2* __restrict__ pl, float* __restrict__ sumsq,
        unsigned* __restrict__ mn, unsigned* __restrict__ mx,
        float* __restrict__ possum, float* __restrict__ negsum,
        unsigned* __restrict__ tval, float* __restrict__ out) {
    int gid = blockIdx.x * 256 + threadIdx.x;   // 8192 threads
    sumsq[gid] = 0.f; mn[gid] = 0xFFFFFFFFu; mx[gid] = 0u;
    possum[gid] = 0.f; negsum[gid] = 0.f;
    if (gid < 64) tval[gid] = 0u;
    if (gid == 0) out[0] = 0.f;

    // hi/lo split: 131072 float4 elements, coalesced
    const float4* F4 = (const float4*)F;
#pragma unroll
    for (int t = 0; t < 16; ++t) {
        int idx = t * 8192 + gid;
        float4 v = F4[idx];
        ushort4 h, l;
        h.x = bf16rne(v.x); l.x = bf16rne(v.x - bf16tof(h.x));
        h.y = bf16rne(v.y); l.y = bf16rne(v.y - bf16tof(h.y));
        h.z = bf16rne(v.z); l.z = bf16rne(v.z - bf16tof(h.z));
        h.w = bf16rne(v.w); l.w = bf16rne(v.w - bf16tof(h.w));
        Fhi[idx] = h; Flo[idx] = l;
    }

    int lane = threadIdx.x & 63;
    int wid = gid >> 6;                 // 128 waves total
    for (int r = 0; r < 64; ++r) {
        int row = wid * 64 + r;
        const int* lr = labels + (size_t)row * NL;
        int v0 = lr[lane];
        int v1 = (lane < 16) ? lr[64 + lane] : 0;
        unsigned long long lo = __ballot(v0 != 0);
        unsigned long long hi = __ballot(v1 != 0);
        if (lane == 0) { pl[row].x = lo; pl[row].y = hi; }
    }
}

#define LDS_AHI 0
#define LDS_ALO 16384

// Stage 128-row A(j) panel only (hi+lo), XOR-swizzled (G4: byte ^= (row&7)<<4).
__device__ __forceinline__ void stage_A(char* lds, const uint4* __restrict__ Fhi4,
        const uint4* __restrict__ Flo4, int j0, int tid) {
#pragma unroll
    for (int t = 0; t < 4; ++t) {
        int idx = tid + t * 256;          // 0..1023
        int row = idx >> 3, c8 = idx & 7;
        int dst = row * 128 + ((c8 * 16) ^ ((row & 7) << 4));
        *(uint4*)(lds + LDS_AHI + dst) = Fhi4[(j0 + row) * 8 + c8];
        *(uint4*)(lds + LDS_ALO + dst) = Flo4[(j0 + row) * 8 + c8];
    }
}

// 64x64 per wave: acc = sum over 3 splits of Fj-panel (LDS) x Fi-panel^T (global/L1).
// C layout (m74/m101): col=lane&31 (i), row=(reg&3)+8*(reg>>2)+4*(lane>>5) (j).
__device__ __forceinline__ void compute_tile(const char* lds,
        const uint4* __restrict__ Fhi4, const uint4* __restrict__ Flo4,
        int i0, int wr, int wc, int lane, f32x16 acc[2][2]) {
    const int l31 = lane & 31, lhalf = lane >> 5;
    const int swz = (l31 & 7) << 4;
    const int abase = (wr * 64 + l31) * 128;
    const size_t brow0 = (size_t)(i0 + wc * 64 + l31) * 8;
#pragma unroll
    for (int seg = 0; seg < 3; ++seg) {
        const char* pa = lds + (seg == 2 ? LDS_ALO : LDS_AHI);
        const uint4* pb = (seg == 1) ? Flo4 : Fhi4;
#pragma unroll
        for (int ks = 0; ks < 4; ++ks) {
            int off = (ks * 32 + lhalf * 16) ^ swz;
            int ci = ks * 2 + lhalf;
            bf16x8 a0 = *(const bf16x8*)(pa + abase + off);
            bf16x8 a1 = *(const bf16x8*)(pa + abase + 32 * 128 + off);
            uint4 ub0 = pb[brow0 + ci];
            uint4 ub1 = pb[brow0 + 32 * 8 + ci];
            bf16x8 b0 = __builtin_bit_cast(bf16x8, ub0);
            bf16x8 b1 = __builtin_bit_cast(bf16x8, ub1);
            acc[0][0] = __builtin_amdgcn_mfma_f32_32x32x16_bf16(a0, b0, acc[0][0], 0, 0, 0);
            acc[0][1] = __builtin_amdgcn_mfma_f32_32x32x16_bf16(a0, b1, acc[0][1], 0, 0, 0);
            acc[1][0] = __builtin_amdgcn_mfma_f32_32x32x16_bf16(a1, b0, acc[1][0], 0, 0, 0);
            acc[1][1] = __builtin_amdgcn_mfma_f32_32x32x16_bf16(a1, b1, acc[1][1], 0, 0, 0);
        }
    }
}

__global__ __launch_bounds__(256, 4) void k_pass1(const uint4* __restrict__ Fhi4,
        const uint4* __restrict__ Flo4, const ulonglong2* __restrict__ pl,
        float* __restrict__ sumsq, unsigned* __restrict__ mn,
        unsigned* __restrict__ mx) {
    __shared__ char lds[32768];
    const int tid = threadIdx.x;
    const int i0 = blockIdx.y * 128, j0 = blockIdx.x * 128;
    stage_A(lds, Fhi4, Flo4, j0, tid);
    __syncthreads();
    const int lane = tid & 63, wid = tid >> 6;
    const int wr = wid >> 1, wc = wid & 1;
    const int l31 = lane & 31, lhalf = lane >> 5;
    f32x16 acc[2][2] = {};
    compute_tile(lds, Fhi4, Flo4, i0, wr, wc, lane, acc);
    __syncthreads();                      // panels dead; reuse LDS for PLj
    if (tid < 128) *(ulonglong2*)(lds + tid * 16) = pl[j0 + tid];
    __syncthreads();

    ulonglong2 pi[2];
    pi[0] = pl[i0 + wc * 64 + l31];
    pi[1] = pl[i0 + wc * 64 + 32 + l31];
    float ssq[2] = {0.f, 0.f};
    float mnp[2] = {INFINITY, INFINITY};
    float mxn[2] = {-INFINITY, -INFINITY};
#pragma unroll
    for (int m = 0; m < 2; ++m) {
#pragma unroll
        for (int reg = 0; reg < 16; ++reg) {
            int jl = wr * 64 + m * 32 + (reg & 3) + 8 * (reg >> 2) + 4 * lhalf;
            ulonglong2 pj = *(const ulonglong2*)(lds + jl * 16);
#pragma unroll
            for (int n = 0; n < 2; ++n) {
                float s = acc[m][n][reg];
                bool pos = (((pi[n].x & pj.x) | (pi[n].y & pj.y)) != 0ull);
                ssq[n] += s * s;
                mnp[n] = fminf(mnp[n], pos ? s : INFINITY);
                mxn[n] = fmaxf(mxn[n], pos ? -INFINITY : s);
            }
        }
    }
#pragma unroll
    for (int n = 0; n < 2; ++n) {
        ssq[n] += __shfl_xor(ssq[n], 32);
        mnp[n] = fminf(mnp[n], __shfl_xor(mnp[n], 32));
        mxn[n] = fmaxf(mxn[n], __shfl_xor(mxn[n], 32));
    }
    if (lane < 32) {
#pragma unroll
        for (int n = 0; n < 2; ++n) {
            int i = i0 + wc * 64 + n * 32 + lane;
            atomicAdd(&sumsq[i], ssq[n]);
            atomicMin(&mn[i], ford(mnp[n]));
            atomicMax(&mx[i], ford(mxn[n]));
        }
    }
}

// Per-row thresholds in RAW-dot space; validity derived from min/max aggregates.
__global__ __launch_bounds__(256) void k_finalize(const float* __restrict__ sumsq,
        const unsigned* __restrict__ mn, const unsigned* __restrict__ mx,
        unsigned* __restrict__ fl, float* __restrict__ tneg, float* __restrict__ tpos,
        float* __restrict__ teps, float* __restrict__ invd, unsigned* __restrict__ tval) {
    int i = blockIdx.x * 256 + threadIdx.x;
    float div = fmaxf(sqrtf(sumsq[i]), 1e-12f);
    float inv = 1.f / div;
    float mp = funord(mn[i]);       // +inf if no pos seen
    float mneg = funord(mx[i]);     // -inf (or NaN if never written) if no neg
    float eraw = (1.0f - 1e-5f) * div;
    bool hasp = (mp < eraw);                    // implies a pos with s < eps exists
    bool hasn = (mneg > -INFINITY);             // NaN/-inf -> false
    float minpos_n = hasp ? mp * inv : INFINITY;
    float maxneg_n = hasn ? mneg * inv : -INFINITY;
    tneg[i] = (minpos_n - 0.1f) * div;   // neg_sel: raw >  tneg
    tpos[i] = (maxneg_n + 0.1f) * div;   // pos_sel: raw <  tpos
    teps[i] = eraw;                      // pos_valid: raw < teps
    invd[i] = inv;
    fl[i] = (hasp ? 1u : 0u) | (hasn ? 2u : 0u);
    if (hasp && hasn) atomicOr(&tval[i >> 7], 1u);   // any valid row in 128-row i-tile
}

__global__ __launch_bounds__(256, 4) void k_pass2(const uint4* __restrict__ Fhi4,
        const uint4* __restrict__ Flo4, const ulonglong2* __restrict__ pl,
        const float* __restrict__ tneg, const float* __restrict__ tpos,
        const float* __restrict__ teps, const float* __restrict__ invd,
        const unsigned* __restrict__ tval,
        float* __restrict__ possum, float* __restrict__ negsum) {
    __shared__ char lds[32768];
    if (tval[blockIdx.y] == 0u) return;   // no valid row in this i-tile: sums unused
    const int tid = threadIdx.x;
    const int i0 = blockIdx.y * 128, j0 = blockIdx.x * 128;
    stage_A(lds, Fhi4, Flo4, j0, tid);
    __syncthreads();
    const int lane = tid & 63, wid = tid >> 6;
    const int wr = wid >> 1, wc = wid & 1;
    const int l31 = lane & 31, lhalf = lane >> 5;
    f32x16 acc[2][2] = {};
    compute_tile(lds, Fhi4, Flo4, i0, wr, wc, lane, acc);
    __syncthreads();
    if (tid < 128) *(ulonglong2*)(lds + tid * 16) = pl[j0 + tid];
    __syncthreads();

    ulonglong2 pi[2];
    float tn[2], tp[2], te[2], iv[2];
#pragma unroll
    for (int n = 0; n < 2; ++n) {
        int i = i0 + wc * 64 + n * 32 + l31;
        pi[n] = pl[i];
        tn[n] = tneg[i]; tp[n] = tpos[i]; te[n] = teps[i]; iv[n] = invd[i];
    }
    float psum[2] = {0.f, 0.f}, nsum[2] = {0.f, 0.f};
#pragma unroll
    for (int m = 0; m < 2; ++m) {
#pragma unroll
        for (int reg = 0; reg < 16; ++reg) {
            int jl = wr * 64 + m * 32 + (reg & 3) + 8 * (reg >> 2) + 4 * lhalf;
            ulonglong2 pj = *(const ulonglong2*)(lds + jl * 16);
#pragma unroll
            for (int n = 0; n < 2; ++n) {
                float s = acc[m][n][reg];
                bool pos = (((pi[n].x & pj.x) | (pi[n].y & pj.y)) != 0ull);
                float sn = s * iv[n];
                bool psel = pos && (s < te[n]) && (s < tp[n]);
                bool nsel = (!pos) && (s > tn[n]);
                float arg = pos ? fmaf(-2.0f, sn, 0.2f) : fmaf(40.0f, sn, -4.0f);
                float ev = __expf(arg);
                psum[n] += psel ? ev : 0.0f;
                nsum[n] += nsel ? ev : 0.0f;
            }
        }
    }
#pragma unroll
    for (int n = 0; n < 2; ++n) {
        psum[n] += __shfl_xor(psum[n], 32);
        nsum[n] += __shfl_xor(nsum[n], 32);
    }
    if (lane < 32) {
#pragma unroll
        for (int n = 0; n < 2; ++n) {
            int i = i0 + wc * 64 + n * 32 + lane;
            atomicAdd(&possum[i], psum[n]);
            atomicAdd(&negsum[i], nsum[n]);
        }
    }
}

__global__ __launch_bounds__(256) void k_reduce(const float* __restrict__ possum,
        const float* __restrict__ negsum, const unsigned* __restrict__ fl,
        float* __restrict__ out) {
    int i = blockIdx.x * 256 + threadIdx.x;
    unsigned f = fl[i];
    float ps = possum[i], ns = negsum[i];
    bool valid = ((f & 1u) != 0u) && ((f & 2u) != 0u) && (ps > 0.f) && (ns > 0.f);
    float rl = valid ? (0.5f * log1pf(ps) + 0.025f * log1pf(ns)) : 0.f;
#pragma unroll
    for (int off = 32; off; off >>= 1) rl += __shfl_xor(rl, off);
    __shared__ float wsum[4];
    if ((threadIdx.x & 63) == 0) wsum[threadIdx.x >> 6] = rl;
    __syncthreads();
    if (threadIdx.x == 0) {
        float s = wsum[0] + wsum[1] + wsum[2] + wsum[3];
        atomicAdd(out, s * (1.0f / 8192.0f));
    }
}

extern "C" void kernel_launch(void* const* d_in, const int* in_sizes, int n_in,
                              void* d_out, int out_size, void* d_ws, size_t ws_size,
                              hipStream_t stream) {
    const float* F = (const float*)d_in[0];
    const int* labels = (const int*)d_in[1];
    float* out = (float*)d_out;

    char* w = (char*)d_ws;
    ulonglong2* pl  = (ulonglong2*)w;                    // 131072 B
    float*    sumsq = (float*)   (w + 131072);
    unsigned* mn    = (unsigned*)(w + 163840);
    unsigned* mx    = (unsigned*)(w + 196608);
    unsigned* fl    = (unsigned*)(w + 229376);
    float*    tneg  = (float*)   (w + 262144);
    float*    tpos  = (float*)   (w + 294912);
    float*    teps  = (float*)   (w + 327680);
    float*    invd  = (float*)   (w + 360448);
    float*    possum= (float*)   (w + 393216);
    float*    negsum= (float*)   (w + 425984);
    unsigned* tval  = (unsigned*)(w + 458752);           // 256 B
    ushort4*  Fhi   = (ushort4*) (w + 462848);           // 1 MB
    ushort4*  Flo   = (ushort4*) (w + 1511424);          // 1 MB, end 2560000

    dim3 g(64, 64);
    k_init<<<32, 256, 0, stream>>>(F, labels, Fhi, Flo, pl, sumsq, mn, mx,
                                   possum, negsum, tval, out);
    k_pass1<<<g, 256, 0, stream>>>((const uint4*)Fhi, (const uint4*)Flo, pl,
                                   sumsq, mn, mx);
    k_finalize<<<32, 256, 0, stream>>>(sumsq, mn, mx, fl, tneg, tpos, teps, invd, tval);
    k_pass2<<<g, 256, 0, stream>>>((const uint4*)Fhi, (const uint4*)Flo, pl,
                                   tneg, tpos, teps, invd, tval, possum, negsum);
    k_reduce<<<32, 256, 0, stream>>>(possum, negsum, fl, out);
}

// Round 4
// 40.014 us; speedup vs baseline: 8.6197x; 3.0478x over previous
//
#include <hip/hip_runtime.h>
#include <math.h>

#define NB 8192
#define ND 64
#define NL 80

typedef __attribute__((ext_vector_type(8))) __bf16 bf16x8;
typedef __attribute__((ext_vector_type(16))) float f32x16;

// order-preserving float <-> uint mapping for atomicMin/Max
__device__ __forceinline__ unsigned ford(float f) {
    unsigned u = __float_as_uint(f);
    return (u & 0x80000000u) ? ~u : (u | 0x80000000u);
}
__device__ __forceinline__ float funord(unsigned u) {
    unsigned v = (u & 0x80000000u) ? (u ^ 0x80000000u) : ~u;
    return __uint_as_float(v);
}
__device__ __forceinline__ unsigned short bf16rne(float x) {
    unsigned u = __float_as_uint(x);
    unsigned r = u + 0x7FFFu + ((u >> 16) & 1u);
    return (unsigned short)(r >> 16);
}
__device__ __forceinline__ float bf16tof(unsigned short h) {
    return __uint_as_float(((unsigned)h) << 16);
}

// Pack labels to 80-bit masks via ballot; zero all stats/flags/out.
__global__ __launch_bounds__(256) void k_pack(const int* __restrict__ labels,
        ulonglong2* __restrict__ pl, float* __restrict__ sumsq,
        unsigned* __restrict__ mn, unsigned* __restrict__ mx,
        float* __restrict__ possum, float* __restrict__ negsum,
        unsigned* __restrict__ tval, unsigned* __restrict__ tneed,
        unsigned* __restrict__ anyneed, float* __restrict__ out) {
    int gid = blockIdx.x * 256 + threadIdx.x;   // 0..32767
    if (gid < 8192) {
        sumsq[gid] = 0.f; mn[gid] = 0xFFFFFFFFu; mx[gid] = 0u;
        possum[gid] = 0.f; negsum[gid] = 0.f;
    }
    if (gid < 64) { tval[gid] = 0u; tneed[gid] = 0u; }
    if (gid == 0) { anyneed[0] = 0u; out[0] = 0.f; }

    int lane = threadIdx.x & 63;
    int wid = gid >> 6;                 // 512 waves
#pragma unroll 1
    for (int r = 0; r < 16; ++r) {
        int row = wid * 16 + r;
        const int* lr = labels + (size_t)row * NL;
        int v0 = lr[lane];
        int v1 = (lane < 16) ? lr[64 + lane] : 0;
        unsigned long long lo = __ballot(v0 != 0);
        unsigned long long hi = __ballot(v1 != 0);
        if (lane == 0) { pl[row].x = lo; pl[row].y = hi; }
    }
}

// Label-only per-row flags: bit0 = any pos-labeled pair, bit1 = any neg-labeled pair.
// lpart[js][row] partials over j-slices of 128. Mask .w is always 0 (bits 80..127).
#define LJS 64
__global__ __launch_bounds__(256) void k_label(const uint4* __restrict__ pl4,
        unsigned char* __restrict__ lpart) {
    __shared__ uint4 PJ[128];
    const int tid = threadIdx.x;
    const int js = blockIdx.x;            // 0..63
    if (tid < 128) PJ[tid] = pl4[js * 128 + tid];
    __syncthreads();
    int r0 = blockIdx.y * 1024 + tid;     // rows r0 + k*256, k=0..3
    uint4 mi[4]; unsigned flg[4] = {0u, 0u, 0u, 0u};
#pragma unroll
    for (int k = 0; k < 4; ++k) mi[k] = pl4[r0 + k * 256];
#pragma unroll 4
    for (int j = 0; j < 128; ++j) {
        uint4 pj = PJ[j];                 // broadcast read
#pragma unroll
        for (int k = 0; k < 4; ++k) {
            unsigned a = (mi[k].x & pj.x) | (mi[k].y & pj.y) | (mi[k].z & pj.z);
            flg[k] |= (a != 0u) ? 1u : 2u;
        }
    }
#pragma unroll
    for (int k = 0; k < 4; ++k)
        lpart[js * 8192 + r0 + k * 256] = (unsigned char)flg[k];
}

// Reduce label partials -> per-128-row-tile need flag + global any flag.
__global__ __launch_bounds__(128) void k_gate(const unsigned char* __restrict__ lpart,
        unsigned* __restrict__ tneed, unsigned* __restrict__ anyneed) {
    int row = blockIdx.x * 128 + threadIdx.x;
    unsigned x = 0u;
#pragma unroll 8
    for (int js = 0; js < LJS; ++js) x |= lpart[js * 8192 + row];
    if ((x & 3u) == 3u) { atomicOr(&tneed[blockIdx.x], 1u); atomicOr(anyneed, 1u); }
}

// Split F into bf16 hi/lo (only when some tile needs the sim pipeline).
__global__ __launch_bounds__(256) void k_split(const float* __restrict__ F,
        ushort4* __restrict__ Fhi, ushort4* __restrict__ Flo,
        const unsigned* __restrict__ anyneed) {
    if (anyneed[0] == 0u) return;
    int gid = blockIdx.x * 256 + threadIdx.x;   // 32768 threads
    const float4* F4 = (const float4*)F;
#pragma unroll
    for (int t = 0; t < 4; ++t) {
        int idx = t * 32768 + gid;
        float4 v = F4[idx];
        ushort4 h, l;
        h.x = bf16rne(v.x); l.x = bf16rne(v.x - bf16tof(h.x));
        h.y = bf16rne(v.y); l.y = bf16rne(v.y - bf16tof(h.y));
        h.z = bf16rne(v.z); l.z = bf16rne(v.z - bf16tof(h.z));
        h.w = bf16rne(v.w); l.w = bf16rne(v.w - bf16tof(h.w));
        Fhi[idx] = h; Flo[idx] = l;
    }
}

#define LDS_AHI 0
#define LDS_ALO 16384

// Stage 128-row A(j) panel (hi+lo), XOR-swizzled (G4: byte ^= (row&7)<<4).
__device__ __forceinline__ void stage_A(char* lds, const uint4* __restrict__ Fhi4,
        const uint4* __restrict__ Flo4, int j0, int tid) {
#pragma unroll
    for (int t = 0; t < 4; ++t) {
        int idx = tid + t * 256;          // 0..1023
        int row = idx >> 3, c8 = idx & 7;
        int dst = row * 128 + ((c8 * 16) ^ ((row & 7) << 4));
        *(uint4*)(lds + LDS_AHI + dst) = Fhi4[(j0 + row) * 8 + c8];
        *(uint4*)(lds + LDS_ALO + dst) = Flo4[(j0 + row) * 8 + c8];
    }
}

// 64x64 per wave: acc = sum over 3 splits of Fj-panel (LDS) x Fi-panel^T (global/L1).
// C layout (m74/m101): col=lane&31 (i), row=(reg&3)+8*(reg>>2)+4*(lane>>5) (j).
__device__ __forceinline__ void compute_tile(const char* lds,
        const uint4* __restrict__ Fhi4, const uint4* __restrict__ Flo4,
        int i0, int wr, int wc, int lane, f32x16 acc[2][2]) {
    const int l31 = lane & 31, lhalf = lane >> 5;
    const int swz = (l31 & 7) << 4;
    const int abase = (wr * 64 + l31) * 128;
    const size_t brow0 = (size_t)(i0 + wc * 64 + l31) * 8;
#pragma unroll
    for (int seg = 0; seg < 3; ++seg) {
        const char* pa = lds + (seg == 2 ? LDS_ALO : LDS_AHI);
        const uint4* pb = (seg == 1) ? Flo4 : Fhi4;
#pragma unroll
        for (int ks = 0; ks < 4; ++ks) {
            int off = (ks * 32 + lhalf * 16) ^ swz;
            int ci = ks * 2 + lhalf;
            bf16x8 a0 = *(const bf16x8*)(pa + abase + off);
            bf16x8 a1 = *(const bf16x8*)(pa + abase + 32 * 128 + off);
            uint4 ub0 = pb[brow0 + ci];
            uint4 ub1 = pb[brow0 + 32 * 8 + ci];
            bf16x8 b0 = __builtin_bit_cast(bf16x8, ub0);
            bf16x8 b1 = __builtin_bit_cast(bf16x8, ub1);
            acc[0][0] = __builtin_amdgcn_mfma_f32_32x32x16_bf16(a0, b0, acc[0][0], 0, 0, 0);
            acc[0][1] = __builtin_amdgcn_mfma_f32_32x32x16_bf16(a0, b1, acc[0][1], 0, 0, 0);
            acc[1][0] = __builtin_amdgcn_mfma_f32_32x32x16_bf16(a1, b0, acc[1][0], 0, 0, 0);
            acc[1][1] = __builtin_amdgcn_mfma_f32_32x32x16_bf16(a1, b1, acc[1][1], 0, 0, 0);
        }
    }
}

__global__ __launch_bounds__(256, 4) void k_pass1(const uint4* __restrict__ Fhi4,
        const uint4* __restrict__ Flo4, const ulonglong2* __restrict__ pl,
        const unsigned* __restrict__ tneed,
        float* __restrict__ sumsq, unsigned* __restrict__ mn,
        unsigned* __restrict__ mx) {
    __shared__ char lds[32768];
    if (tneed[blockIdx.y] == 0u) return;  // label-level gate: no row can be valid
    const int tid = threadIdx.x;
    const int i0 = blockIdx.y * 128, j0 = blockIdx.x * 128;
    stage_A(lds, Fhi4, Flo4, j0, tid);
    __syncthreads();
    const int lane = tid & 63, wid = tid >> 6;
    const int wr = wid >> 1, wc = wid & 1;
    const int l31 = lane & 31, lhalf = lane >> 5;
    f32x16 acc[2][2] = {};
    compute_tile(lds, Fhi4, Flo4, i0, wr, wc, lane, acc);
    __syncthreads();                      // panels dead; reuse LDS for PLj
    if (tid < 128) *(ulonglong2*)(lds + tid * 16) = pl[j0 + tid];
    __syncthreads();

    ulonglong2 pi[2];
    pi[0] = pl[i0 + wc * 64 + l31];
    pi[1] = pl[i0 + wc * 64 + 32 + l31];
    float ssq[2] = {0.f, 0.f};
    float mnp[2] = {INFINITY, INFINITY};
    float mxn[2] = {-INFINITY, -INFINITY};
#pragma unroll
    for (int m = 0; m < 2; ++m) {
#pragma unroll
        for (int reg = 0; reg < 16; ++reg) {
            int jl = wr * 64 + m * 32 + (reg & 3) + 8 * (reg >> 2) + 4 * lhalf;
            ulonglong2 pj = *(const ulonglong2*)(lds + jl * 16);
#pragma unroll
            for (int n = 0; n < 2; ++n) {
                float s = acc[m][n][reg];
                bool pos = (((pi[n].x & pj.x) | (pi[n].y & pj.y)) != 0ull);
                ssq[n] += s * s;
                mnp[n] = fminf(mnp[n], pos ? s : INFINITY);
                mxn[n] = fmaxf(mxn[n], pos ? -INFINITY : s);
            }
        }
    }
#pragma unroll
    for (int n = 0; n < 2; ++n) {
        ssq[n] += __shfl_xor(ssq[n], 32);
        mnp[n] = fminf(mnp[n], __shfl_xor(mnp[n], 32));
        mxn[n] = fmaxf(mxn[n], __shfl_xor(mxn[n], 32));
    }
    if (lane < 32) {
#pragma unroll
        for (int n = 0; n < 2; ++n) {
            int i = i0 + wc * 64 + n * 32 + lane;
            atomicAdd(&sumsq[i], ssq[n]);
            atomicMin(&mn[i], ford(mnp[n]));
            atomicMax(&mx[i], ford(mxn[n]));
        }
    }
}

// Per-row thresholds in RAW-dot space; validity derived from min/max aggregates.
__global__ __launch_bounds__(256) void k_finalize(const float* __restrict__ sumsq,
        const unsigned* __restrict__ mn, const unsigned* __restrict__ mx,
        unsigned* __restrict__ fl, float* __restrict__ tneg, float* __restrict__ tpos,
        float* __restrict__ teps, float* __restrict__ invd, unsigned* __restrict__ tval) {
    int i = blockIdx.x * 256 + threadIdx.x;
    float div = fmaxf(sqrtf(sumsq[i]), 1e-12f);
    float inv = 1.f / div;
    float mp = funord(mn[i]);       // +inf/NaN if no pos seen
    float mneg = funord(mx[i]);     // -inf/NaN if no neg seen
    float eraw = (1.0f - 1e-5f) * div;
    bool hasp = (mp < eraw);
    bool hasn = (mneg > -INFINITY);             // NaN/-inf -> false
    float minpos_n = hasp ? mp * inv : INFINITY;
    float maxneg_n = hasn ? mneg * inv : -INFINITY;
    tneg[i] = (minpos_n - 0.1f) * div;   // neg_sel: raw >  tneg
    tpos[i] = (maxneg_n + 0.1f) * div;   // pos_sel: raw <  tpos
    teps[i] = eraw;                      // pos_valid: raw < teps
    invd[i] = inv;
    fl[i] = (hasp ? 1u : 0u) | (hasn ? 2u : 0u);
    if (hasp && hasn) atomicOr(&tval[i >> 7], 1u);   // any valid row in i-tile
}

__global__ __launch_bounds__(256, 4) void k_pass2(const uint4* __restrict__ Fhi4,
        const uint4* __restrict__ Flo4, const ulonglong2* __restrict__ pl,
        const float* __restrict__ tneg, const float* __restrict__ tpos,
        const float* __restrict__ teps, const float* __restrict__ invd,
        const unsigned* __restrict__ tval,
        float* __restrict__ possum, float* __restrict__ negsum) {
    __shared__ char lds[32768];
    if (tval[blockIdx.y] == 0u) return;   // no valid row in this i-tile: sums unused
    const int tid = threadIdx.x;
    const int i0 = blockIdx.y * 128, j0 = blockIdx.x * 128;
    stage_A(lds, Fhi4, Flo4, j0, tid);
    __syncthreads();
    const int lane = tid & 63, wid = tid >> 6;
    const int wr = wid >> 1, wc = wid & 1;
    const int l31 = lane & 31, lhalf = lane >> 5;
    f32x16 acc[2][2] = {};
    compute_tile(lds, Fhi4, Flo4, i0, wr, wc, lane, acc);
    __syncthreads();
    if (tid < 128) *(ulonglong2*)(lds + tid * 16) = pl[j0 + tid];
    __syncthreads();

    ulonglong2 pi[2];
    float tn[2], tp[2], te[2], iv[2];
#pragma unroll
    for (int n = 0; n < 2; ++n) {
        int i = i0 + wc * 64 + n * 32 + l31;
        pi[n] = pl[i];
        tn[n] = tneg[i]; tp[n] = tpos[i]; te[n] = teps[i]; iv[n] = invd[i];
    }
    float psum[2] = {0.f, 0.f}, nsum[2] = {0.f, 0.f};
#pragma unroll
    for (int m = 0; m < 2; ++m) {
#pragma unroll
        for (int reg = 0; reg < 16; ++reg) {
            int jl = wr * 64 + m * 32 + (reg & 3) + 8 * (reg >> 2) + 4 * lhalf;
            ulonglong2 pj = *(const ulonglong2*)(lds + jl * 16);
#pragma unroll
            for (int n = 0; n < 2; ++n) {
                float s = acc[m][n][reg];
                bool pos = (((pi[n].x & pj.x) | (pi[n].y & pj.y)) != 0ull);
                float sn = s * iv[n];
                bool psel = pos && (s < te[n]) && (s < tp[n]);
                bool nsel = (!pos) && (s > tn[n]);
                float arg = pos ? fmaf(-2.0f, sn, 0.2f) : fmaf(40.0f, sn, -4.0f);
                float ev = __expf(arg);
                psum[n] += psel ? ev : 0.0f;
                nsum[n] += nsel ? ev : 0.0f;
            }
        }
    }
#pragma unroll
    for (int n = 0; n < 2; ++n) {
        psum[n] += __shfl_xor(psum[n], 32);
        nsum[n] += __shfl_xor(nsum[n], 32);
    }
    if (lane < 32) {
#pragma unroll
        for (int n = 0; n < 2; ++n) {
            int i = i0 + wc * 64 + n * 32 + lane;
            atomicAdd(&possum[i], psum[n]);
            atomicAdd(&negsum[i], nsum[n]);
        }
    }
}

__global__ __launch_bounds__(256) void k_reduce(const float* __restrict__ possum,
        const float* __restrict__ negsum, const unsigned* __restrict__ fl,
        float* __restrict__ out) {
    int i = blockIdx.x * 256 + threadIdx.x;
    unsigned f = fl[i];
    float ps = possum[i], ns = negsum[i];
    bool valid = (f == 3u) && (ps > 0.f) && (ns > 0.f);
    float rl = valid ? (0.5f * log1pf(ps) + 0.025f * log1pf(ns)) : 0.f;
#pragma unroll
    for (int off = 32; off; off >>= 1) rl += __shfl_xor(rl, off);
    __shared__ float wsum[4];
    if ((threadIdx.x & 63) == 0) wsum[threadIdx.x >> 6] = rl;
    __syncthreads();
    if (threadIdx.x == 0) {
        float s = wsum[0] + wsum[1] + wsum[2] + wsum[3];
        atomicAdd(out, s * (1.0f / 8192.0f));
    }
}

extern "C" void kernel_launch(void* const* d_in, const int* in_sizes, int n_in,
                              void* d_out, int out_size, void* d_ws, size_t ws_size,
                              hipStream_t stream) {
    const float* F = (const float*)d_in[0];
    const int* labels = (const int*)d_in[1];
    float* out = (float*)d_out;

    char* w = (char*)d_ws;
    ulonglong2* pl  = (ulonglong2*)w;                    // 131072 B
    float*    sumsq = (float*)   (w + 131072);
    unsigned* mn    = (unsigned*)(w + 163840);
    unsigned* mx    = (unsigned*)(w + 196608);
    unsigned* fl    = (unsigned*)(w + 229376);
    float*    tneg  = (float*)   (w + 262144);
    float*    tpos  = (float*)   (w + 294912);
    float*    teps  = (float*)   (w + 327680);
    float*    invd  = (float*)   (w + 360448);
    float*    possum= (float*)   (w + 393216);
    float*    negsum= (float*)   (w + 425984);
    unsigned* tval  = (unsigned*)(w + 458752);           // 256 B
    unsigned* tneed = (unsigned*)(w + 459008);           // 256 B
    unsigned* anyneed=(unsigned*)(w + 459264);           // 4 B (pad to 4 KB)
    ushort4*  Fhi   = (ushort4*) (w + 462848);           // 1 MB
    ushort4*  Flo   = (ushort4*) (w + 1511424);          // 1 MB, end 2560000
    unsigned char* lpart = (unsigned char*)Fhi;          // 512 KB alias (dead before split)

    dim3 g(64, 64);
    k_pack<<<128, 256, 0, stream>>>(labels, pl, sumsq, mn, mx, possum, negsum,
                                    tval, tneed, anyneed, out);
    k_label<<<dim3(LJS, 8), 256, 0, stream>>>((const uint4*)pl, lpart);
    k_gate<<<64, 128, 0, stream>>>(lpart, tneed, anyneed);
    k_split<<<128, 256, 0, stream>>>(F, Fhi, Flo, anyneed);
    k_pass1<<<g, 256, 0, stream>>>((const uint4*)Fhi, (const uint4*)Flo, pl, tneed,
                                   sumsq, mn, mx);
    k_finalize<<<32, 256, 0, stream>>>(sumsq, mn, mx, fl, tneg, tpos, teps, invd, tval);
    k_pass2<<<g, 256, 0, stream>>>((const uint4*)Fhi, (const uint4*)Flo, pl,
                                   tneg, tpos, teps, invd, tval, possum, negsum);
    k_reduce<<<32, 256, 0, stream>>>(possum, negsum, fl, out);
}

// Round 5
// 31.215 us; speedup vs baseline: 11.0494x; 1.2819x over previous
//
#include <hip/hip_runtime.h>
#include <math.h>

#define NB 8192
#define ND 64
#define NL 80

typedef __attribute__((ext_vector_type(8))) __bf16 bf16x8;
typedef __attribute__((ext_vector_type(16))) float f32x16;

// order-preserving float <-> uint mapping for atomicMin/Max
__device__ __forceinline__ unsigned ford(float f) {
    unsigned u = __float_as_uint(f);
    return (u & 0x80000000u) ? ~u : (u | 0x80000000u);
}
__device__ __forceinline__ float funord(unsigned u) {
    unsigned v = (u & 0x80000000u) ? (u ^ 0x80000000u) : ~u;
    return __uint_as_float(v);
}
__device__ __forceinline__ unsigned short bf16rne(float x) {
    unsigned u = __float_as_uint(x);
    unsigned r = u + 0x7FFFu + ((u >> 16) & 1u);
    return (unsigned short)(r >> 16);
}
__device__ __forceinline__ float bf16tof(unsigned short h) {
    return __uint_as_float(((unsigned)h) << 16);
}

// Pack labels to 80-bit masks via ballot (1 wave : 4 rows); zero pf/tneed/anyneed.
__global__ __launch_bounds__(256) void k_pack(const int* __restrict__ labels,
        ulonglong2* __restrict__ pl, unsigned* __restrict__ pf,
        unsigned* __restrict__ tneed, unsigned* __restrict__ anyneed) {
    int gid = blockIdx.x * 256 + threadIdx.x;   // 0..131071
    if (gid < 2048) pf[gid] = 0u;
    if (gid < 64) tneed[gid] = 0u;
    if (gid == 0) anyneed[0] = 0u;

    int lane = threadIdx.x & 63;
    int w = gid >> 6;                           // 0..2047 waves
    const int* base = labels + (size_t)w * 4 * NL;
#pragma unroll
    for (int r = 0; r < 4; ++r) {
        int v0 = base[r * NL + lane];
        int v1 = (lane < 16) ? base[r * NL + 64 + lane] : 0;
        unsigned long long lo = __ballot(v0 != 0);
        unsigned long long hi = __ballot(v1 != 0);
        if (lane == 0) { pl[w * 4 + r].x = lo; pl[w * 4 + r].y = hi; }
    }
}

// Label-only row flags. hasPosLab <=> mask != 0 (diagonal). hasNeg <=> min_j(u)==0.
// pf[row>>2] bits (row&3)*2: bit0=pos, bit1=neg. grid (128 j-slices of 64, 8 row-grps).
__global__ __launch_bounds__(256) void k_label(const uint4* __restrict__ pl4,
        unsigned* __restrict__ pf) {
    __shared__ uint4 PJ[64];
    const int tid = threadIdx.x;
    if (tid < 64) PJ[tid] = pl4[blockIdx.x * 64 + tid];
    __syncthreads();
    const int r0 = blockIdx.y * 1024 + tid * 4;   // 4 consecutive rows
    uint4 mi[4];
    unsigned nm[4] = {0xFFFFFFFFu, 0xFFFFFFFFu, 0xFFFFFFFFu, 0xFFFFFFFFu};
#pragma unroll
    for (int k = 0; k < 4; ++k) mi[k] = pl4[r0 + k];
#pragma unroll 4
    for (int j = 0; j < 64; ++j) {
        uint4 pj = PJ[j];
#pragma unroll
        for (int k = 0; k < 4; ++k) {
            unsigned u = (mi[k].x & pj.x) | (mi[k].y & pj.y) | (mi[k].z & pj.z);
            nm[k] = min(nm[k], u);
        }
    }
    unsigned word = 0u;
#pragma unroll
    for (int k = 0; k < 4; ++k) {
        unsigned pos = ((mi[k].x | mi[k].y | mi[k].z) != 0u) ? 1u : 0u;
        unsigned neg = (nm[k] == 0u) ? 2u : 0u;
        word |= (pos | neg) << (k * 2);
    }
    atomicOr(&pf[r0 >> 2], word);
}

// Derive per-tile need flags; zero all per-row stats and out.
__global__ __launch_bounds__(256) void k_gate2(const unsigned* __restrict__ pf,
        float* __restrict__ sumsq, unsigned* __restrict__ mn, unsigned* __restrict__ mx,
        float* __restrict__ possum, float* __restrict__ negsum,
        unsigned* __restrict__ tneed, unsigned* __restrict__ anyneed,
        float* __restrict__ out) {
    int i = blockIdx.x * 256 + threadIdx.x;     // 0..8191
    sumsq[i] = 0.f; mn[i] = 0xFFFFFFFFu; mx[i] = 0u;
    possum[i] = 0.f; negsum[i] = 0.f;
    if (i == 0) out[0] = 0.f;
    unsigned bits = (pf[i >> 2] >> ((i & 3) * 2)) & 3u;
    bool need = (bits == 3u);
    int anyw = __any((int)need);
    if ((threadIdx.x & 63) == 0 && anyw) {
        atomicOr(&tneed[i >> 7], 1u);
        atomicOr(anyneed, 1u);
    }
}

// Split F into bf16 hi/lo (only when some tile needs the sim pipeline).
__global__ __launch_bounds__(256) void k_split(const float* __restrict__ F,
        ushort4* __restrict__ Fhi, ushort4* __restrict__ Flo,
        const unsigned* __restrict__ anyneed) {
    if (anyneed[0] == 0u) return;
    int gid = blockIdx.x * 256 + threadIdx.x;   // 32768 threads
    const float4* F4 = (const float4*)F;
#pragma unroll
    for (int t = 0; t < 4; ++t) {
        int idx = t * 32768 + gid;
        float4 v = F4[idx];
        ushort4 h, l;
        h.x = bf16rne(v.x); l.x = bf16rne(v.x - bf16tof(h.x));
        h.y = bf16rne(v.y); l.y = bf16rne(v.y - bf16tof(h.y));
        h.z = bf16rne(v.z); l.z = bf16rne(v.z - bf16tof(h.z));
        h.w = bf16rne(v.w); l.w = bf16rne(v.w - bf16tof(h.w));
        Fhi[idx] = h; Flo[idx] = l;
    }
}

#define LDS_AHI 0
#define LDS_ALO 16384
#define LDS_PL  32768
#define LDS_TH  34816

// Stage 128-row A(j) panel (hi+lo), XOR-swizzled (G4: byte ^= (row&7)<<4).
__device__ __forceinline__ void stage_A(char* lds, const uint4* __restrict__ Fhi4,
        const uint4* __restrict__ Flo4, int j0, int tid) {
#pragma unroll
    for (int t = 0; t < 4; ++t) {
        int idx = tid + t * 256;          // 0..1023
        int row = idx >> 3, c8 = idx & 7;
        int dst = row * 128 + ((c8 * 16) ^ ((row & 7) << 4));
        *(uint4*)(lds + LDS_AHI + dst) = Fhi4[(j0 + row) * 8 + c8];
        *(uint4*)(lds + LDS_ALO + dst) = Flo4[(j0 + row) * 8 + c8];
    }
}

// 64x64 per wave: acc = sum over 3 splits of Fj-panel (LDS) x Fi-panel^T (global/L1).
// C layout (m74/m101): col=lane&31 (i), row=(reg&3)+8*(reg>>2)+4*(lane>>5) (j).
__device__ __forceinline__ void compute_tile(const char* lds,
        const uint4* __restrict__ Fhi4, const uint4* __restrict__ Flo4,
        int i0, int wr, int wc, int lane, f32x16 acc[2][2]) {
    const int l31 = lane & 31, lhalf = lane >> 5;
    const int swz = (l31 & 7) << 4;
    const int abase = (wr * 64 + l31) * 128;
    const size_t brow0 = (size_t)(i0 + wc * 64 + l31) * 8;
#pragma unroll
    for (int seg = 0; seg < 3; ++seg) {
        const char* pa = lds + (seg == 2 ? LDS_ALO : LDS_AHI);
        const uint4* pb = (seg == 1) ? Flo4 : Fhi4;
#pragma unroll
        for (int ks = 0; ks < 4; ++ks) {
            int off = (ks * 32 + lhalf * 16) ^ swz;
            int ci = ks * 2 + lhalf;
            bf16x8 a0 = *(const bf16x8*)(pa + abase + off);
            bf16x8 a1 = *(const bf16x8*)(pa + abase + 32 * 128 + off);
            uint4 ub0 = pb[brow0 + ci];
            uint4 ub1 = pb[brow0 + 32 * 8 + ci];
            bf16x8 b0 = __builtin_bit_cast(bf16x8, ub0);
            bf16x8 b1 = __builtin_bit_cast(bf16x8, ub1);
            acc[0][0] = __builtin_amdgcn_mfma_f32_32x32x16_bf16(a0, b0, acc[0][0], 0, 0, 0);
            acc[0][1] = __builtin_amdgcn_mfma_f32_32x32x16_bf16(a0, b1, acc[0][1], 0, 0, 0);
            acc[1][0] = __builtin_amdgcn_mfma_f32_32x32x16_bf16(a1, b0, acc[1][0], 0, 0, 0);
            acc[1][1] = __builtin_amdgcn_mfma_f32_32x32x16_bf16(a1, b1, acc[1][1], 0, 0, 0);
        }
    }
}

// Pass 1: grid (8 j-chunks, 64 i-tiles); j-loop of 8x128 inside. Stats in regs,
// one atomic set per block (8 per row total instead of 64).
__global__ __launch_bounds__(256, 4) void k_pass1(const uint4* __restrict__ Fhi4,
        const uint4* __restrict__ Flo4, const ulonglong2* __restrict__ pl,
        const unsigned* __restrict__ tneed,
        float* __restrict__ sumsq, unsigned* __restrict__ mn,
        unsigned* __restrict__ mx) {
    __shared__ char lds[34816];
    if (tneed[blockIdx.y] == 0u) return;
    const int tid = threadIdx.x;
    const int i0 = blockIdx.y * 128;
    const int lane = tid & 63, wid = tid >> 6;
    const int wr = wid >> 1, wc = wid & 1;
    const int l31 = lane & 31, lhalf = lane >> 5;
    ulonglong2 pi[2];
    pi[0] = pl[i0 + wc * 64 + l31];
    pi[1] = pl[i0 + wc * 64 + 32 + l31];
    float ssq[2] = {0.f, 0.f};
    float mnp[2] = {INFINITY, INFINITY};
    float mxn[2] = {-INFINITY, -INFINITY};

    for (int jj = 0; jj < 8; ++jj) {
        const int j0 = blockIdx.x * 1024 + jj * 128;
        __syncthreads();                  // prior epilogue done reading LDS
        stage_A(lds, Fhi4, Flo4, j0, tid);
        if (tid < 128) *(ulonglong2*)(lds + LDS_PL + tid * 16) = pl[j0 + tid];
        __syncthreads();
        f32x16 acc[2][2] = {};
        compute_tile(lds, Fhi4, Flo4, i0, wr, wc, lane, acc);
#pragma unroll
        for (int m = 0; m < 2; ++m) {
#pragma unroll
            for (int reg = 0; reg < 16; ++reg) {
                int jl = wr * 64 + m * 32 + (reg & 3) + 8 * (reg >> 2) + 4 * lhalf;
                ulonglong2 pj = *(const ulonglong2*)(lds + LDS_PL + jl * 16);
#pragma unroll
                for (int n = 0; n < 2; ++n) {
                    float s = acc[m][n][reg];
                    bool pos = (((pi[n].x & pj.x) | (pi[n].y & pj.y)) != 0ull);
                    ssq[n] += s * s;
                    mnp[n] = fminf(mnp[n], pos ? s : INFINITY);
                    mxn[n] = fmaxf(mxn[n], pos ? -INFINITY : s);
                }
            }
        }
    }
#pragma unroll
    for (int n = 0; n < 2; ++n) {
        ssq[n] += __shfl_xor(ssq[n], 32);
        mnp[n] = fminf(mnp[n], __shfl_xor(mnp[n], 32));
        mxn[n] = fmaxf(mxn[n], __shfl_xor(mxn[n], 32));
    }
    if (lane < 32) {
#pragma unroll
        for (int n = 0; n < 2; ++n) {
            int i = i0 + wc * 64 + n * 32 + lane;
            atomicAdd(&sumsq[i], ssq[n]);
            atomicMin(&mn[i], ford(mnp[n]));
            atomicMax(&mx[i], ford(mxn[n]));
        }
    }
}

// Pass 2: recomputes per-row thresholds from pass1 aggregates (no finalize kernel),
// skips if no valid row in tile; j-loop of 8x128.
__global__ __launch_bounds__(256, 4) void k_pass2(const uint4* __restrict__ Fhi4,
        const uint4* __restrict__ Flo4, const ulonglong2* __restrict__ pl,
        const unsigned* __restrict__ tneed,
        const float* __restrict__ sumsq, const unsigned* __restrict__ mn,
        const unsigned* __restrict__ mx,
        float* __restrict__ possum, float* __restrict__ negsum) {
    __shared__ char lds[36864];
    __shared__ int anyvalid;
    if (tneed[blockIdx.y] == 0u) return;
    const int tid = threadIdx.x;
    const int i0 = blockIdx.y * 128;
    if (tid == 0) anyvalid = 0;
    __syncthreads();
    if (tid < 128) {
        int i = i0 + tid;
        float div = fmaxf(sqrtf(sumsq[i]), 1e-12f);
        float inv = 1.f / div;
        float mp = funord(mn[i]);        // +inf/NaN if no pos seen
        float mng = funord(mx[i]);       // -inf/NaN if no neg seen
        float eraw = (1.0f - 1e-5f) * div;
        bool hasp = (mp < eraw);
        bool hasn = (mng > -INFINITY);
        float minpos_n = hasp ? mp * inv : INFINITY;
        float maxneg_n = hasn ? mng * inv : -INFINITY;
        float4 th;
        th.x = (minpos_n - 0.1f) * div;  // tneg: neg_sel iff raw > tneg
        th.y = (maxneg_n + 0.1f) * div;  // tpos: pos_sel iff raw < tpos
        th.z = eraw;                     // pos_valid: raw < teps
        th.w = inv;
        *(float4*)(lds + LDS_TH + tid * 16) = th;
        if (hasp && hasn) anyvalid = 1;
    }
    __syncthreads();
    if (anyvalid == 0) return;

    const int lane = tid & 63, wid = tid >> 6;
    const int wr = wid >> 1, wc = wid & 1;
    const int l31 = lane & 31, lhalf = lane >> 5;
    ulonglong2 pi[2];
    float tn[2], tp[2], te[2], iv[2];
#pragma unroll
    for (int n = 0; n < 2; ++n) {
        int ii = wc * 64 + n * 32 + l31;
        pi[n] = pl[i0 + ii];
        float4 th = *(const float4*)(lds + LDS_TH + ii * 16);
        tn[n] = th.x; tp[n] = th.y; te[n] = th.z; iv[n] = th.w;
    }
    float psum[2] = {0.f, 0.f}, nsum[2] = {0.f, 0.f};

    for (int jj = 0; jj < 8; ++jj) {
        const int j0 = blockIdx.x * 1024 + jj * 128;
        __syncthreads();
        stage_A(lds, Fhi4, Flo4, j0, tid);
        if (tid < 128) *(ulonglong2*)(lds + LDS_PL + tid * 16) = pl[j0 + tid];
        __syncthreads();
        f32x16 acc[2][2] = {};
        compute_tile(lds, Fhi4, Flo4, i0, wr, wc, lane, acc);
#pragma unroll
        for (int m = 0; m < 2; ++m) {
#pragma unroll
            for (int reg = 0; reg < 16; ++reg) {
                int jl = wr * 64 + m * 32 + (reg & 3) + 8 * (reg >> 2) + 4 * lhalf;
                ulonglong2 pj = *(const ulonglong2*)(lds + LDS_PL + jl * 16);
#pragma unroll
                for (int n = 0; n < 2; ++n) {
                    float s = acc[m][n][reg];
                    bool pos = (((pi[n].x & pj.x) | (pi[n].y & pj.y)) != 0ull);
                    float sn = s * iv[n];
                    bool psel = pos && (s < te[n]) && (s < tp[n]);
                    bool nsel = (!pos) && (s > tn[n]);
                    float arg = pos ? fmaf(-2.0f, sn, 0.2f) : fmaf(40.0f, sn, -4.0f);
                    float ev = __expf(arg);
                    psum[n] += psel ? ev : 0.0f;
                    nsum[n] += nsel ? ev : 0.0f;
                }
            }
        }
    }
#pragma unroll
    for (int n = 0; n < 2; ++n) {
        psum[n] += __shfl_xor(psum[n], 32);
        nsum[n] += __shfl_xor(nsum[n], 32);
    }
    if (lane < 32) {
#pragma unroll
        for (int n = 0; n < 2; ++n) {
            int i = i0 + wc * 64 + n * 32 + lane;
            atomicAdd(&possum[i], psum[n]);
            atomicAdd(&negsum[i], nsum[n]);
        }
    }
}

// Final: recompute row validity from aggregates, sum row losses.
__global__ __launch_bounds__(256) void k_reduce(const float* __restrict__ possum,
        const float* __restrict__ negsum, const float* __restrict__ sumsq,
        const unsigned* __restrict__ mn, const unsigned* __restrict__ mx,
        float* __restrict__ out) {
    int i = blockIdx.x * 256 + threadIdx.x;
    float div = fmaxf(sqrtf(sumsq[i]), 1e-12f);
    float mp = funord(mn[i]);
    float mng = funord(mx[i]);
    float eraw = (1.0f - 1e-5f) * div;
    bool hasp = (mp < eraw);
    bool hasn = (mng > -INFINITY);
    float ps = possum[i], ns = negsum[i];
    bool valid = hasp && hasn && (ps > 0.f) && (ns > 0.f);
    float rl = valid ? (0.5f * log1pf(ps) + 0.025f * log1pf(ns)) : 0.f;
#pragma unroll
    for (int off = 32; off; off >>= 1) rl += __shfl_xor(rl, off);
    __shared__ float wsum[4];
    if ((threadIdx.x & 63) == 0) wsum[threadIdx.x >> 6] = rl;
    __syncthreads();
    if (threadIdx.x == 0) {
        float s = wsum[0] + wsum[1] + wsum[2] + wsum[3];
        atomicAdd(out, s * (1.0f / 8192.0f));
    }
}

extern "C" void kernel_launch(void* const* d_in, const int* in_sizes, int n_in,
                              void* d_out, int out_size, void* d_ws, size_t ws_size,
                              hipStream_t stream) {
    const float* F = (const float*)d_in[0];
    const int* labels = (const int*)d_in[1];
    float* out = (float*)d_out;

    char* w = (char*)d_ws;
    ulonglong2* pl   = (ulonglong2*)w;                   // 131072 B
    float*    sumsq  = (float*)   (w + 131072);          // 32 KB
    unsigned* mn     = (unsigned*)(w + 163840);
    unsigned* mx     = (unsigned*)(w + 196608);
    float*    possum = (float*)   (w + 229376);
    float*    negsum = (float*)   (w + 262144);
    unsigned* pf     = (unsigned*)(w + 294912);          // 8192 B (2048 u32)
    unsigned* tneed  = (unsigned*)(w + 303104);          // 256 B
    unsigned* anyneed= (unsigned*)(w + 303360);          // 4 B
    ushort4*  Fhi    = (ushort4*) (w + 307200);          // 1 MB
    ushort4*  Flo    = (ushort4*) (w + 1355776);         // 1 MB, end 2404352

    k_pack<<<512, 256, 0, stream>>>(labels, pl, pf, tneed, anyneed);
    k_label<<<dim3(128, 8), 256, 0, stream>>>((const uint4*)pl, pf);
    k_gate2<<<32, 256, 0, stream>>>(pf, sumsq, mn, mx, possum, negsum,
                                    tneed, anyneed, out);
    k_split<<<128, 256, 0, stream>>>(F, Fhi, Flo, anyneed);
    k_pass1<<<dim3(8, 64), 256, 0, stream>>>((const uint4*)Fhi, (const uint4*)Flo,
                                             pl, tneed, sumsq, mn, mx);
    k_pass2<<<dim3(8, 64), 256, 0, stream>>>((const uint4*)Fhi, (const uint4*)Flo,
                                             pl, tneed, sumsq, mn, mx, possum, negsum);
    k_reduce<<<32, 256, 0, stream>>>(possum, negsum, sumsq, mn, mx, out);
}

// Round 7
// 20.990 us; speedup vs baseline: 16.4321x; 1.4871x over previous
//
#include <hip/hip_runtime.h>
#include <math.h>

#define NB 8192
#define ND 64
#define NL 80

typedef __attribute__((ext_vector_type(8))) __bf16 bf16x8;
typedef __attribute__((ext_vector_type(16))) float f32x16;

// LDS layout for k_heavy (40960 B, phase-multiplexed)
#define LDS_AHI 0
#define LDS_ALO 16384
#define LDS_PL  32768
#define LDS_TH  34816
#define LDS_VAL 36864
#define LDS_SCR 37376
#define LDS_ANY 40448
#define LDS_WS  40452

__device__ __forceinline__ unsigned bf16rne(float x) {
    unsigned u = __float_as_uint(x);
    unsigned r = u + 0x7FFFu + ((u >> 16) & 1u);
    return r >> 16;
}
__device__ __forceinline__ float bf16tof(unsigned h) {
    return __uint_as_float(h << 16);
}

// 8 floats -> 8 bf16 hi (uint4) + 8 bf16 lo (uint4)
__device__ __forceinline__ void split8(float4 va, float4 vb, uint4* hi, uint4* lo) {
    float f[8] = {va.x, va.y, va.z, va.w, vb.x, vb.y, vb.z, vb.w};
    unsigned h[8], l[8];
#pragma unroll
    for (int k = 0; k < 8; ++k) {
        h[k] = bf16rne(f[k]);
        l[k] = bf16rne(f[k] - bf16tof(h[k]));
    }
    *hi = make_uint4(h[0] | (h[1] << 16), h[2] | (h[3] << 16),
                     h[4] | (h[5] << 16), h[6] | (h[7] << 16));
    *lo = make_uint4(l[0] | (l[1] << 16), l[2] | (l[3] << 16),
                     l[4] | (l[5] << 16), l[6] | (l[7] << 16));
}

// ---- K1: ballot-pack labels into 80-bit masks; zero tneed/out ----
__global__ __launch_bounds__(256) void k_pack(const int* __restrict__ labels,
        ulonglong2* __restrict__ pl, unsigned* __restrict__ tneed,
        float* __restrict__ out) {
    int gid = blockIdx.x * 256 + threadIdx.x;   // 512 blocks -> 2048 waves
    if (gid < 64) tneed[gid] = 0u;
    if (gid == 0) out[0] = 0.f;
    int lane = threadIdx.x & 63;
    int w = gid >> 6;                           // 0..2047, 4 rows each
    const int* base = labels + (size_t)w * 4 * NL;
#pragma unroll
    for (int r = 0; r < 4; ++r) {
        int v0 = base[r * NL + lane];
        int v1 = (lane < 16) ? base[r * NL + 64 + lane] : 0;
        unsigned long long lo = __ballot(v0 != 0);
        unsigned long long hi = __ballot(v1 != 0);
        if (lane == 0) { pl[w * 4 + r].x = lo; pl[w * 4 + r].y = hi; }
    }
}

// ---- K2: label-only need flags -> tneed, directly ----
// need(row) = (mask != 0  [diagonal => has pos-labeled pair]) && (exists j disjoint).
// Partial per j-slice is exact for the OR-aggregation into the 128-row tile flag.
__global__ __launch_bounds__(256) void k_label(const uint4* __restrict__ pl4,
        unsigned* __restrict__ tneed) {
    __shared__ uint4 PJ[64];
    const int tid = threadIdx.x;
    if (tid < 64) PJ[tid] = pl4[blockIdx.x * 64 + tid];
    __syncthreads();
    const int r0 = blockIdx.y * 1024 + tid * 4;   // 4 consecutive rows
    uint4 mi[4];
    unsigned nm[4] = {0xFFFFFFFFu, 0xFFFFFFFFu, 0xFFFFFFFFu, 0xFFFFFFFFu};
#pragma unroll
    for (int k = 0; k < 4; ++k) mi[k] = pl4[r0 + k];
#pragma unroll 4
    for (int j = 0; j < 64; ++j) {
        uint4 pj = PJ[j];
#pragma unroll
        for (int k = 0; k < 4; ++k) {
            unsigned u = (mi[k].x & pj.x) | (mi[k].y & pj.y) | (mi[k].z & pj.z);
            nm[k] = min(nm[k], u);
        }
    }
    bool need = false;
#pragma unroll
    for (int k = 0; k < 4; ++k) {
        bool pos = (mi[k].x | mi[k].y | mi[k].z) != 0u;
        need = need || (pos && nm[k] == 0u);
    }
    if (need) atomicOr(&tneed[r0 >> 7], 1u);
}

// ---- K3 helpers: fp32 -> bf16 hi/lo on the fly ----
// Stage 128-row A(j) panel, XOR-swizzled (G4: byte ^= (row&7)<<4).
__device__ __forceinline__ void stage_A(char* lds, const float4* __restrict__ F4,
        int j0, int tid) {
#pragma unroll
    for (int t = 0; t < 4; ++t) {
        int idx = tid + t * 256;          // 0..1023
        int row = idx >> 3, c8 = idx & 7;
        float4 v0 = F4[(size_t)(j0 + row) * 16 + c8 * 2];
        float4 v1 = F4[(size_t)(j0 + row) * 16 + c8 * 2 + 1];
        uint4 hi, lo;
        split8(v0, v1, &hi, &lo);
        int dst = row * 128 + ((c8 * 16) ^ ((row & 7) << 4));
        *(uint4*)(lds + LDS_AHI + dst) = hi;
        *(uint4*)(lds + LDS_ALO + dst) = lo;
    }
}

// 64x64 per wave: acc = 3-split product of Fj-panel (LDS) x Fi-panel^T (global fp32).
// C layout (m74/m101): col=lane&31 (i), row=(reg&3)+8*(reg>>2)+4*(lane>>5) (j).
__device__ __forceinline__ void compute_tile(const char* lds,
        const float4* __restrict__ F4, int i0, int wr, int wc, int lane,
        f32x16 acc[2][2]) {
    const int l31 = lane & 31, lhalf = lane >> 5;
    const int swz = (l31 & 7) << 4;
    const int abase = (wr * 64 + l31) * 128;
    const size_t br0 = (size_t)(i0 + wc * 64 + l31) * 16;
    const size_t br1 = br0 + 32 * 16;
#pragma unroll
    for (int ks = 0; ks < 4; ++ks) {
        int off = (ks * 32 + lhalf * 16) ^ swz;
        int ci = ks * 2 + lhalf;
        bf16x8 a0h = *(const bf16x8*)(lds + LDS_AHI + abase + off);
        bf16x8 a1h = *(const bf16x8*)(lds + LDS_AHI + abase + 32 * 128 + off);
        bf16x8 a0l = *(const bf16x8*)(lds + LDS_ALO + abase + off);
        bf16x8 a1l = *(const bf16x8*)(lds + LDS_ALO + abase + 32 * 128 + off);
        uint4 b0hu, b0lu, b1hu, b1lu;
        split8(F4[br0 + ci * 2], F4[br0 + ci * 2 + 1], &b0hu, &b0lu);
        split8(F4[br1 + ci * 2], F4[br1 + ci * 2 + 1], &b1hu, &b1lu);
        bf16x8 b0h = __builtin_bit_cast(bf16x8, b0hu);
        bf16x8 b0l = __builtin_bit_cast(bf16x8, b0lu);
        bf16x8 b1h = __builtin_bit_cast(bf16x8, b1hu);
        bf16x8 b1l = __builtin_bit_cast(bf16x8, b1lu);
        acc[0][0] = __builtin_amdgcn_mfma_f32_32x32x16_bf16(a0h, b0h, acc[0][0], 0, 0, 0);
        acc[0][0] = __builtin_amdgcn_mfma_f32_32x32x16_bf16(a0h, b0l, acc[0][0], 0, 0, 0);
        acc[0][0] = __builtin_amdgcn_mfma_f32_32x32x16_bf16(a0l, b0h, acc[0][0], 0, 0, 0);
        acc[0][1] = __builtin_amdgcn_mfma_f32_32x32x16_bf16(a0h, b1h, acc[0][1], 0, 0, 0);
        acc[0][1] = __builtin_amdgcn_mfma_f32_32x32x16_bf16(a0h, b1l, acc[0][1], 0, 0, 0);
        acc[0][1] = __builtin_amdgcn_mfma_f32_32x32x16_bf16(a0l, b1h, acc[0][1], 0, 0, 0);
        acc[1][0] = __builtin_amdgcn_mfma_f32_32x32x16_bf16(a1h, b0h, acc[1][0], 0, 0, 0);
        acc[1][0] = __builtin_amdgcn_mfma_f32_32x32x16_bf16(a1h, b0l, acc[1][0], 0, 0, 0);
        acc[1][0] = __builtin_amdgcn_mfma_f32_32x32x16_bf16(a1l, b0h, acc[1][0], 0, 0, 0);
        acc[1][1] = __builtin_amdgcn_mfma_f32_32x32x16_bf16(a1h, b1h, acc[1][1], 0, 0, 0);
        acc[1][1] = __builtin_amdgcn_mfma_f32_32x32x16_bf16(a1h, b1l, acc[1][1], 0, 0, 0);
        acc[1][1] = __builtin_amdgcn_mfma_f32_32x32x16_bf16(a1l, b1h, acc[1][1], 0, 0, 0);
    }
}

// ---- K3: gated full sim pipeline, one block per 128-row i-tile ----
__global__ __launch_bounds__(256, 1) void k_heavy(const float* __restrict__ F,
        const ulonglong2* __restrict__ pl, const unsigned* __restrict__ tneed,
        float* __restrict__ out) {
    __shared__ char lds[40960];
    const int b = blockIdx.x;
    if (tneed[b] == 0u) return;           // label-level gate (block-uniform)
    const float4* F4 = (const float4*)F;
    const int t = threadIdx.x;
    const int i0 = b * 128;
    const int lane = t & 63, wv = t >> 6;
    const int wr = wv >> 1, wc = wv & 1;
    const int l31 = lane & 31, lhalf = lane >> 5;

    ulonglong2 pi[2];
    pi[0] = pl[i0 + wc * 64 + l31];
    pi[1] = pl[i0 + wc * 64 + 32 + l31];

    // ---- pass 1: full j-range, stats in regs ----
    float ssq[2] = {0.f, 0.f};
    float mnp[2] = {INFINITY, INFINITY};
    float mxn[2] = {-INFINITY, -INFINITY};
    for (int js = 0; js < 64; ++js) {
        const int j0 = js * 128;
        __syncthreads();
        stage_A(lds, F4, j0, t);
        if (t < 128) *(ulonglong2*)(lds + LDS_PL + t * 16) = pl[j0 + t];
        __syncthreads();
        f32x16 acc[2][2] = {};
        compute_tile(lds, F4, i0, wr, wc, lane, acc);
#pragma unroll
        for (int m = 0; m < 2; ++m) {
#pragma unroll
            for (int reg = 0; reg < 16; ++reg) {
                int jl = wr * 64 + m * 32 + (reg & 3) + 8 * (reg >> 2) + 4 * lhalf;
                ulonglong2 pj = *(const ulonglong2*)(lds + LDS_PL + jl * 16);
#pragma unroll
                for (int n = 0; n < 2; ++n) {
                    float s = acc[m][n][reg];
                    bool pos = (((pi[n].x & pj.x) | (pi[n].y & pj.y)) != 0ull);
                    ssq[n] += s * s;
                    mnp[n] = fminf(mnp[n], pos ? s : INFINITY);
                    mxn[n] = fmaxf(mxn[n], pos ? -INFINITY : s);
                }
            }
        }
    }
#pragma unroll
    for (int n = 0; n < 2; ++n) {
        ssq[n] += __shfl_xor(ssq[n], 32);
        mnp[n] = fminf(mnp[n], __shfl_xor(mnp[n], 32));
        mxn[n] = fmaxf(mxn[n], __shfl_xor(mxn[n], 32));
    }
    float* SC2 = (float*)(lds + LDS_SCR);
    int* ANYV = (int*)(lds + LDS_ANY);
    if (lane < 32) {
#pragma unroll
        for (int n = 0; n < 2; ++n) {
            int il = wc * 64 + n * 32 + lane;
            SC2[(wr * 128 + il) * 3 + 0] = ssq[n];
            SC2[(wr * 128 + il) * 3 + 1] = mnp[n];
            SC2[(wr * 128 + il) * 3 + 2] = mxn[n];
        }
    }
    if (t == 0) *ANYV = 0;
    __syncthreads();
    // ---- per-row thresholds (raw-dot space, verified R0-R5 logic) ----
    if (t < 128) {
        float s2 = SC2[t * 3] + SC2[(128 + t) * 3];
        float mp = fminf(SC2[t * 3 + 1], SC2[(128 + t) * 3 + 1]);
        float mg = fmaxf(SC2[t * 3 + 2], SC2[(128 + t) * 3 + 2]);
        float div = fmaxf(sqrtf(s2), 1e-12f);
        float inv = 1.f / div;
        float eraw = (1.0f - 1e-5f) * div;
        bool hasp = (mp < eraw);
        bool hasn = (mg > -INFINITY);
        float minpos_n = hasp ? mp * inv : INFINITY;
        float maxneg_n = hasn ? mg * inv : -INFINITY;
        float4 th;
        th.x = (minpos_n - 0.1f) * div;   // neg_sel: raw > th.x
        th.y = (maxneg_n + 0.1f) * div;   // pos_sel: raw < th.y
        th.z = eraw;                      // pos_valid: raw < th.z
        th.w = inv;
        *(float4*)(lds + LDS_TH + t * 16) = th;
        ((int*)(lds + LDS_VAL))[t] = (hasp && hasn) ? 1 : 0;
        if (hasp && hasn) *ANYV = 1;
    }
    __syncthreads();
    if (*ANYV == 0) return;               // block-uniform

    // ---- pass 2: mined exp sums ----
    float tn[2], tp[2], te[2], iv[2];
#pragma unroll
    for (int n = 0; n < 2; ++n) {
        int il = wc * 64 + n * 32 + l31;
        float4 th = *(const float4*)(lds + LDS_TH + il * 16);
        tn[n] = th.x; tp[n] = th.y; te[n] = th.z; iv[n] = th.w;
    }
    float psum[2] = {0.f, 0.f}, nsum[2] = {0.f, 0.f};
    for (int js = 0; js < 64; ++js) {
        const int j0 = js * 128;
        __syncthreads();
        stage_A(lds, F4, j0, t);
        if (t < 128) *(ulonglong2*)(lds + LDS_PL + t * 16) = pl[j0 + t];
        __syncthreads();
        f32x16 acc[2][2] = {};
        compute_tile(lds, F4, i0, wr, wc, lane, acc);
#pragma unroll
        for (int m = 0; m < 2; ++m) {
#pragma unroll
            for (int reg = 0; reg < 16; ++reg) {
                int jl = wr * 64 + m * 32 + (reg & 3) + 8 * (reg >> 2) + 4 * lhalf;
                ulonglong2 pj = *(const ulonglong2*)(lds + LDS_PL + jl * 16);
#pragma unroll
                for (int n = 0; n < 2; ++n) {
                    float s = acc[m][n][reg];
                    bool pos = (((pi[n].x & pj.x) | (pi[n].y & pj.y)) != 0ull);
                    float sn = s * iv[n];
                    bool psel = pos && (s < te[n]) && (s < tp[n]);
                    bool nsel = (!pos) && (s > tn[n]);
                    float arg = pos ? fmaf(-2.0f, sn, 0.2f) : fmaf(40.0f, sn, -4.0f);
                    float ev = __expf(arg);
                    psum[n] += psel ? ev : 0.0f;
                    nsum[n] += nsel ? ev : 0.0f;
                }
            }
        }
    }
#pragma unroll
    for (int n = 0; n < 2; ++n) {
        psum[n] += __shfl_xor(psum[n], 32);
        nsum[n] += __shfl_xor(nsum[n], 32);
    }
    __syncthreads();                      // SC2 reuse: threshold reads done
    if (lane < 32) {
#pragma unroll
        for (int n = 0; n < 2; ++n) {
            int il = wc * 64 + n * 32 + lane;
            SC2[(wr * 128 + il) * 2 + 0] = psum[n];
            SC2[(wr * 128 + il) * 2 + 1] = nsum[n];
        }
    }
    __syncthreads();
    // ---- row losses + block sum -> out ----
    float rl = 0.f;
    if (t < 128) {
        float ps = SC2[t * 2] + SC2[(128 + t) * 2];
        float ns = SC2[t * 2 + 1] + SC2[(128 + t) * 2 + 1];
        int val = ((int*)(lds + LDS_VAL))[t];
        rl = (val && ps > 0.f && ns > 0.f)
                 ? (0.5f * log1pf(ps) + 0.025f * log1pf(ns)) : 0.f;
    }
#pragma unroll
    for (int off = 32; off; off >>= 1) rl += __shfl_xor(rl, off);
    float* WS = (float*)(lds + LDS_WS);
    __syncthreads();
    if (lane == 0) WS[wv] = rl;
    __syncthreads();
    if (t == 0) atomicAdd(out, (WS[0] + WS[1] + WS[2] + WS[3]) * (1.0f / 8192.0f));
}

extern "C" void kernel_launch(void* const* d_in, const int* in_sizes, int n_in,
                              void* d_out, int out_size, void* d_ws, size_t ws_size,
                              hipStream_t stream) {
    const float* F = (const float*)d_in[0];
    const int* labels = (const int*)d_in[1];
    float* out = (float*)d_out;

    char* w = (char*)d_ws;
    ulonglong2* pl  = (ulonglong2*)w;                    // 131072 B
    unsigned* tneed = (unsigned*)(w + 131072);           // 256 B

    k_pack<<<512, 256, 0, stream>>>(labels, pl, tneed, out);
    k_label<<<dim3(128, 8), 256, 0, stream>>>((const uint4*)pl, tneed);
    k_heavy<<<64, 256, 0, stream>>>(F, pl, tneed, out);
}